// Round 1
// baseline (2311.018 us; speedup 1.0000x reference)
//
#include <hip/hip_runtime.h>
#include <math.h>

#define VSZ   30522
#define DIM   768
#define KDELT 768
#define BOT   512
#define BATCH 256
#define MNEG  4096
#define EPSN  1e-6f
#define TEMPC 0.05f

static __device__ __forceinline__ float gelu_exact(float x){
    return 0.5f * x * (1.0f + erff(x * 0.70710678118654752440f));
}
static __device__ __forceinline__ float softplus_f(float x){
    return fmaxf(x, 0.0f) + log1pf(expf(-fabsf(x)));
}

// ---------------------------------------------------------------------------
// Tiled fp32 GEMM: Cpart[s] = A[M,K(lda)] * B[K,N(ldb)] over K-chunk s.
// BM=BN=64, BK=16, 256 threads, 4x4 microtile. Scalar global loads (rows of
// stride 30522 are only 8B-aligned). NGUARD: N not multiple of 64.
// ---------------------------------------------------------------------------
template<bool NGUARD>
__global__ __launch_bounds__(256) void gemm_ab_part(
    const float* __restrict__ A, int lda,
    const float* __restrict__ B, int ldb,
    float* __restrict__ Cpart,
    int M, int N, int K, int nsplit)
{
    constexpr int BM = 64, BN = 64, BK = 16;
    __shared__ float As[BK][BM];
    __shared__ float Bs[BK][BN];
    const int t  = threadIdx.x;
    const int m0 = blockIdx.x * BM;
    const int n0 = blockIdx.y * BN;
    const int s  = blockIdx.z;
    const int kchunk  = (K + nsplit - 1) / nsplit;
    const int k_begin = s * kchunk;
    const int k_end   = min(K, k_begin + kchunk);

    const int a_m  = t >> 2;          // 0..63
    const int a_kq = (t & 3) << 2;    // 0,4,8,12
    const int b_kk = t >> 4;          // 0..15
    const int b_nq = (t & 15) << 2;   // 0..60
    const int ty   = t >> 4, tx = t & 15;

    float acc[4][4] = {};

    for (int k0 = k_begin; k0 < k_end; k0 += BK) {
        const int krem = k_end - k0;
        {
            const float* ap = A + (size_t)(m0 + a_m) * lda + k0 + a_kq;
            float a0 = (a_kq + 0 < krem) ? ap[0] : 0.f;
            float a1 = (a_kq + 1 < krem) ? ap[1] : 0.f;
            float a2 = (a_kq + 2 < krem) ? ap[2] : 0.f;
            float a3 = (a_kq + 3 < krem) ? ap[3] : 0.f;
            As[a_kq + 0][a_m] = a0; As[a_kq + 1][a_m] = a1;
            As[a_kq + 2][a_m] = a2; As[a_kq + 3][a_m] = a3;
        }
        {
            float b0 = 0.f, b1 = 0.f, b2 = 0.f, b3 = 0.f;
            if (b_kk < krem) {
                const float* bp = B + (size_t)(k0 + b_kk) * ldb + n0 + b_nq;
                if (!NGUARD || n0 + b_nq + 3 < N) {
                    b0 = bp[0]; b1 = bp[1]; b2 = bp[2]; b3 = bp[3];
                } else {
                    if (n0 + b_nq + 0 < N) b0 = bp[0];
                    if (n0 + b_nq + 1 < N) b1 = bp[1];
                    if (n0 + b_nq + 2 < N) b2 = bp[2];
                    if (n0 + b_nq + 3 < N) b3 = bp[3];
                }
            }
            Bs[b_kk][b_nq + 0] = b0; Bs[b_kk][b_nq + 1] = b1;
            Bs[b_kk][b_nq + 2] = b2; Bs[b_kk][b_nq + 3] = b3;
        }
        __syncthreads();
        #pragma unroll
        for (int kk = 0; kk < BK; kk++) {
            float4 av = *(const float4*)&As[kk][ty << 2];
            float4 bv = *(const float4*)&Bs[kk][tx << 2];
            float a[4] = {av.x, av.y, av.z, av.w};
            float b[4] = {bv.x, bv.y, bv.z, bv.w};
            #pragma unroll
            for (int i = 0; i < 4; i++)
                #pragma unroll
                for (int j = 0; j < 4; j++)
                    acc[i][j] = fmaf(a[i], b[j], acc[i][j]);
        }
        __syncthreads();
    }

    float* Cp = Cpart + (size_t)s * M * N;
    #pragma unroll
    for (int i = 0; i < 4; i++) {
        const int m = m0 + (ty << 2) + i;
        #pragma unroll
        for (int j = 0; j < 4; j++) {
            const int n = n0 + (tx << 2) + j;
            if (!NGUARD || n < N)
                Cp[(size_t)m * N + n] = acc[i][j];
        }
    }
}

// C[m,n] = (A[m,:] . B2[n,:]) / TEMP   (A:[M,K], B2:[N,K], K%16==0)
__global__ __launch_bounds__(256) void gemm_abt(
    const float* __restrict__ A, const float* __restrict__ B2,
    float* __restrict__ C, int M, int N, int K)
{
    constexpr int BM = 64, BN = 64, BK = 16;
    __shared__ float As[BK][BM];
    __shared__ float Bs[BK][BN];
    const int t  = threadIdx.x;
    const int m0 = blockIdx.x * BM, n0 = blockIdx.y * BN;
    const int l_r = t >> 2, l_kq = (t & 3) << 2;
    const int ty = t >> 4, tx = t & 15;
    float acc[4][4] = {};
    for (int k0 = 0; k0 < K; k0 += BK) {
        const float* ap = A  + (size_t)(m0 + l_r) * K + k0 + l_kq;
        As[l_kq + 0][l_r] = ap[0]; As[l_kq + 1][l_r] = ap[1];
        As[l_kq + 2][l_r] = ap[2]; As[l_kq + 3][l_r] = ap[3];
        const float* bp = B2 + (size_t)(n0 + l_r) * K + k0 + l_kq;
        Bs[l_kq + 0][l_r] = bp[0]; Bs[l_kq + 1][l_r] = bp[1];
        Bs[l_kq + 2][l_r] = bp[2]; Bs[l_kq + 3][l_r] = bp[3];
        __syncthreads();
        #pragma unroll
        for (int kk = 0; kk < BK; kk++) {
            float4 av = *(const float4*)&As[kk][ty << 2];
            float4 bv = *(const float4*)&Bs[kk][tx << 2];
            float a[4] = {av.x, av.y, av.z, av.w};
            float b[4] = {bv.x, bv.y, bv.z, bv.w};
            #pragma unroll
            for (int i = 0; i < 4; i++)
                #pragma unroll
                for (int j = 0; j < 4; j++)
                    acc[i][j] = fmaf(a[i], b[j], acc[i][j]);
        }
        __syncthreads();
    }
    #pragma unroll
    for (int i = 0; i < 4; i++)
        #pragma unroll
        for (int j = 0; j < 4; j++)
            C[(size_t)(m0 + (ty << 2) + i) * N + n0 + (tx << 2) + j] =
                acc[i][j] / TEMPC;
}

__global__ __launch_bounds__(256) void reduce_bias_gelu(
    const float* __restrict__ P, const float* __restrict__ bias,
    float* __restrict__ H, int M, int N, int nsplit)
{
    const int idx = blockIdx.x * 256 + threadIdx.x;
    if (idx >= M * N) return;
    const int n = idx % N;
    float s = 0.f;
    for (int k = 0; k < nsplit; k++) s += P[(size_t)k * M * N + idx];
    H[idx] = gelu_exact(s + bias[n]);
}

__global__ __launch_bounds__(256) void softplus_bias_inplace(
    float* __restrict__ U, const float* __restrict__ bias, int M, int N)
{
    const size_t total = (size_t)M * N;
    for (size_t idx = (size_t)blockIdx.x * 256 + threadIdx.x; idx < total;
         idx += (size_t)gridDim.x * 256) {
        const int n = (int)(idx % N);
        U[idx] = softplus_f(U[idx] + bias[n]);
    }
}

__global__ __launch_bounds__(256) void reduce_sum_parts(
    const float* __restrict__ P, float* __restrict__ Y, int MN, int nsplit)
{
    const int idx = blockIdx.x * 256 + threadIdx.x;
    if (idx >= MN) return;
    float s = 0.f;
    for (int k = 0; k < nsplit; k++) s += P[(size_t)k * MN + idx];
    Y[idx] = s;
}

// Per-row exact K-th-largest via 4-pass radix select on float bits (all >=0).
__global__ __launch_bounds__(256) void topk_thresh(
    const float* __restrict__ U, int N, int Kq, float* __restrict__ tout)
{
    __shared__ unsigned int hist[256];
    __shared__ unsigned int s_pref;
    __shared__ int s_rem;
    const int row = blockIdx.x, t = threadIdx.x;
    const float* u = U + (size_t)row * N;
    unsigned int pref = 0, pmask = 0;
    int remain = Kq;
    for (int pass = 0; pass < 4; pass++) {
        const int shift = 24 - 8 * pass;
        hist[t] = 0;
        __syncthreads();
        for (int j = t; j < N; j += 256) {
            const unsigned int v = __float_as_uint(u[j]);
            if ((v & pmask) == pref) atomicAdd(&hist[(v >> shift) & 0xFFu], 1u);
        }
        __syncthreads();
        if (t == 0) {
            unsigned int cum = 0; int b = 255;
            for (; b >= 0; b--) {
                const unsigned int h = hist[b];
                if (cum + h >= (unsigned int)remain) break;
                cum += h;
            }
            if (b < 0) b = 0;
            s_pref = pref | ((unsigned int)b << shift);
            s_rem  = remain - (int)cum;
        }
        __syncthreads();
        pref = s_pref; remain = s_rem;
        pmask |= (0xFFu << shift);
        __syncthreads();
    }
    if (t == 0) tout[row] = __uint_as_float(pref);
}

// U1 := clip(sr + dsp,0) - clip(dsm,0); row-sums of dsp/dsm for loss_sparse.
__global__ __launch_bounds__(256) void build_sq(
    float* __restrict__ U1, const float* __restrict__ U2,
    const float* __restrict__ sr,
    const float* __restrict__ tp, const float* __restrict__ tm,
    float* __restrict__ sparse_p, float* __restrict__ sparse_m)
{
    __shared__ float red[256];
    const int row = blockIdx.x, t = threadIdx.x;
    const float thp = tp[row], thm = tm[row];
    float* u1 = U1 + (size_t)row * VSZ;
    const float* u2 = U2 + (size_t)row * VSZ;
    const float* s  = sr + (size_t)row * VSZ;
    float sp = 0.f, sm = 0.f;
    for (int j = t; j < VSZ; j += 256) {
        const float up = u1[j], um = u2[j];
        const float dp = (up >= thp) ? up : 0.f;
        const float dm = (um >= thm) ? um : 0.f;
        sp += dp; sm += dm;
        u1[j] = fmaxf(s[j] + dp, 0.f) - fmaxf(dm, 0.f);
    }
    red[t] = sp; __syncthreads();
    for (int o = 128; o > 0; o >>= 1) { if (t < o) red[t] += red[t + o]; __syncthreads(); }
    if (t == 0) sparse_p[row] = red[0];
    __syncthreads();
    red[t] = sm; __syncthreads();
    for (int o = 128; o > 0; o >>= 1) { if (t < o) red[t] += red[t + o]; __syncthreads(); }
    if (t == 0) sparse_m[row] = red[0];
}

__global__ __launch_bounds__(256) void rownorm(
    const float* __restrict__ X, float* __restrict__ Y, int dbl)
{
    __shared__ float red[256];
    const int row = blockIdx.x, t = threadIdx.x;
    const float* x = X + (size_t)row * DIM;
    float* y = Y + (size_t)row * DIM;
    float v0 = x[t], v1 = x[t + 256], v2 = x[t + 512];
    red[t] = v0 * v0 + v1 * v1 + v2 * v2; __syncthreads();
    for (int o = 128; o > 0; o >>= 1) { if (t < o) red[t] += red[t + o]; __syncthreads(); }
    const float nrm = sqrtf(red[0]) + EPSN;
    v0 /= nrm; v1 /= nrm; v2 /= nrm;
    if (dbl) {
        __syncthreads();
        red[t] = v0 * v0 + v1 * v1 + v2 * v2; __syncthreads();
        for (int o = 128; o > 0; o >>= 1) { if (t < o) red[t] += red[t + o]; __syncthreads(); }
        const float n2 = sqrtf(red[0]) + EPSN;
        v0 /= n2; v1 /= n2; v2 /= n2;
    }
    y[t] = v0; y[t + 256] = v1; y[t + 512] = v2;
}

__global__ __launch_bounds__(256) void pos_dot(
    const float* __restrict__ zq, const float* __restrict__ zp,
    float* __restrict__ posL)
{
    __shared__ float red[256];
    const int row = blockIdx.x, t = threadIdx.x;
    const float* a = zq + (size_t)row * DIM;
    const float* b = zp + (size_t)row * DIM;
    red[t] = a[t] * b[t] + a[t + 256] * b[t + 256] + a[t + 512] * b[t + 512];
    __syncthreads();
    for (int o = 128; o > 0; o >>= 1) { if (t < o) red[t] += red[t + o]; __syncthreads(); }
    if (t == 0) posL[row] = red[0] / TEMPC;
}

__global__ __launch_bounds__(256) void lse_loss(
    const float* __restrict__ negL, const float* __restrict__ posL,
    float* __restrict__ rowL)
{
    __shared__ float red[256];
    const int row = blockIdx.x, t = threadIdx.x;
    const float* nl = negL + (size_t)row * MNEG;
    const float p = posL[row];
    float lmax = (t == 0) ? p : -INFINITY;
    for (int j = t; j < MNEG; j += 256) lmax = fmaxf(lmax, nl[j]);
    red[t] = lmax; __syncthreads();
    for (int o = 128; o > 0; o >>= 1) { if (t < o) red[t] = fmaxf(red[t], red[t + o]); __syncthreads(); }
    const float mx = red[0];
    __syncthreads();
    float lsum = (t == 0) ? expf(p - mx) : 0.f;
    for (int j = t; j < MNEG; j += 256) lsum += expf(nl[j] - mx);
    red[t] = lsum; __syncthreads();
    for (int o = 128; o > 0; o >>= 1) { if (t < o) red[t] += red[t + o]; __syncthreads(); }
    if (t == 0) rowL[row] = mx + logf(red[0]) - p;
}

__global__ __launch_bounds__(256) void rec_row(
    const float* __restrict__ zhat, const float* __restrict__ zrn,
    float* __restrict__ part)
{
    __shared__ float red[256];
    const int row = blockIdx.x, t = threadIdx.x;
    const float* a = zhat + (size_t)row * DIM;
    const float* b = zrn + (size_t)row * DIM;
    const float d0 = a[t] - b[t], d1 = a[t + 256] - b[t + 256], d2 = a[t + 512] - b[t + 512];
    red[t] = d0 * d0 + d1 * d1 + d2 * d2;
    __syncthreads();
    for (int o = 128; o > 0; o >>= 1) { if (t < o) red[t] += red[t + o]; __syncthreads(); }
    if (t == 0) part[row] = red[0];
}

__global__ __launch_bounds__(256) void final_combine(
    const float* __restrict__ rowL, const float* __restrict__ recP,
    const float* __restrict__ spP, const float* __restrict__ spM,
    float* __restrict__ out)
{
    __shared__ float red[256];
    const int t = threadIdx.x;
    red[t] = rowL[t]; __syncthreads();
    for (int o = 128; o > 0; o >>= 1) { if (t < o) red[t] += red[t + o]; __syncthreads(); }
    const float retr = red[0] / 256.0f;
    __syncthreads();
    red[t] = recP[t]; __syncthreads();
    for (int o = 128; o > 0; o >>= 1) { if (t < o) red[t] += red[t + o]; __syncthreads(); }
    const float rec = red[0] / (float)(BATCH * DIM);
    __syncthreads();
    red[t] = spP[t] + spM[t]; __syncthreads();
    for (int o = 128; o > 0; o >>= 1) { if (t < o) red[t] += red[t + o]; __syncthreads(); }
    const float sparse = red[0] / 256.0f;
    if (t == 0) out[0] = retr + 1.0f * rec + 1e-4f * sparse;
}

extern "C" void kernel_launch(void* const* d_in, const int* in_sizes, int n_in,
                              void* d_out, int out_size, void* d_ws, size_t ws_size,
                              hipStream_t stream)
{
    const float* ht   = (const float*)d_in[0];
    const float* sr   = (const float*)d_in[1];
    const float* zpos = (const float*)d_in[2];
    const float* zneg = (const float*)d_in[3];
    const float* zr   = (const float*)d_in[4];
    const float* W1p  = (const float*)d_in[5];
    const float* b1p  = (const float*)d_in[6];
    const float* W2p  = (const float*)d_in[7];
    const float* b2p  = (const float*)d_in[8];
    const float* W1m  = (const float*)d_in[9];
    const float* b1m  = (const float*)d_in[10];
    const float* W2m  = (const float*)d_in[11];
    const float* b2m  = (const float*)d_in[12];
    const float* Wdec = (const float*)d_in[13];
    float* out = (float*)d_out;

    // workspace layout (bytes)
    char* ws = (char*)d_ws;
    float* U1   = (float*)(ws + 0);           // 256*30522*4 = 31,254,528  (u_p -> sq)
    float* U2   = (float*)(ws + 31254528);    // 31,254,528               (u_m)
    float* H    = (float*)(ws + 62509056);    // 524,288                  (hidden)
    float* P    = (float*)(ws + 63033344);    // 6,291,456  gemm1 partials / P3a
    float* P3b  = (float*)(ws + 69324800);    // 6,291,456
    float* Y1   = (float*)(ws + 75616256);    // 786,432   sq@Wdec -> zq_n (in place)
    float* Y2   = (float*)(ws + 76402688);    // 786,432   sr@Wdec -> zhat_n
    float* Zn   = (float*)(ws + 77189120);    // 12,582,912 z_neg normalized
    float* Zp   = (float*)(ws + 89772032);    // 786,432
    float* Zrn  = (float*)(ws + 90558464);    // 786,432
    float* NegL = (float*)(ws + 91344896);    // 4,194,304
    float* tP   = (float*)(ws + 95539200);    // 256 each below
    float* tM   = tP + 256;
    float* spP  = tP + 512;
    float* spM  = tP + 768;
    float* posL = tP + 1024;
    float* rowL = tP + 1280;
    float* recP = tP + 1536;
    (void)in_sizes; (void)n_in; (void)out_size; (void)ws_size;

    const dim3 blk(256);

    // ---- branch p: u_p = softplus(gelu(ht@W1p + b1p)@W2p + b2p)
    gemm_ab_part<false><<<dim3(4, 8, 8), blk, 0, stream>>>(ht, VSZ, W1p, BOT, P, BATCH, BOT, VSZ, 8);
    reduce_bias_gelu<<<dim3(512), blk, 0, stream>>>(P, b1p, H, BATCH, BOT, 8);
    gemm_ab_part<true><<<dim3(4, 477, 1), blk, 0, stream>>>(H, BOT, W2p, VSZ, U1, BATCH, VSZ, BOT, 1);
    softplus_bias_inplace<<<dim3(2048), blk, 0, stream>>>(U1, b2p, BATCH, VSZ);
    topk_thresh<<<dim3(256), blk, 0, stream>>>(U1, VSZ, KDELT, tP);

    // ---- branch m
    gemm_ab_part<false><<<dim3(4, 8, 8), blk, 0, stream>>>(ht, VSZ, W1m, BOT, P, BATCH, BOT, VSZ, 8);
    reduce_bias_gelu<<<dim3(512), blk, 0, stream>>>(P, b1m, H, BATCH, BOT, 8);
    gemm_ab_part<true><<<dim3(4, 477, 1), blk, 0, stream>>>(H, BOT, W2m, VSZ, U2, BATCH, VSZ, BOT, 1);
    softplus_bias_inplace<<<dim3(2048), blk, 0, stream>>>(U2, b2m, BATCH, VSZ);
    topk_thresh<<<dim3(256), blk, 0, stream>>>(U2, VSZ, KDELT, tM);

    // ---- sq (in place into U1) + sparse row sums
    build_sq<<<dim3(256), blk, 0, stream>>>(U1, U2, sr, tP, tM, spP, spM);

    // ---- decode GEMMs (split-K 8)
    gemm_ab_part<false><<<dim3(4, 12, 8), blk, 0, stream>>>(U1, VSZ, Wdec, DIM, P,   BATCH, DIM, VSZ, 8);
    gemm_ab_part<false><<<dim3(4, 12, 8), blk, 0, stream>>>(sr, VSZ, Wdec, DIM, P3b, BATCH, DIM, VSZ, 8);
    reduce_sum_parts<<<dim3(768), blk, 0, stream>>>(P,   Y1, BATCH * DIM, 8);
    reduce_sum_parts<<<dim3(768), blk, 0, stream>>>(P3b, Y2, BATCH * DIM, 8);

    // ---- normalizations
    rownorm<<<dim3(256),  blk, 0, stream>>>(Y1, Y1, 1);   // zq (double norm)
    rownorm<<<dim3(256),  blk, 0, stream>>>(Y2, Y2, 0);   // zhat_r
    rownorm<<<dim3(4096), blk, 0, stream>>>(zneg, Zn, 0);
    rownorm<<<dim3(256),  blk, 0, stream>>>(zpos, Zp, 0);
    rownorm<<<dim3(256),  blk, 0, stream>>>(zr,   Zrn, 0);

    // ---- retrieval loss
    pos_dot<<<dim3(256), blk, 0, stream>>>(Y1, Zp, posL);
    gemm_abt<<<dim3(4, 64), blk, 0, stream>>>(Y1, Zn, NegL, BATCH, MNEG, DIM);
    lse_loss<<<dim3(256), blk, 0, stream>>>(NegL, posL, rowL);

    // ---- reconstruction loss
    rec_row<<<dim3(256), blk, 0, stream>>>(Y2, Zrn, recP);

    // ---- combine
    final_combine<<<dim3(1), blk, 0, stream>>>(rowL, recP, spP, spM, out);
}

// Round 2
// 2310.310 us; speedup vs baseline: 1.0003x; 1.0003x over previous
//
#include <hip/hip_runtime.h>
#include <math.h>

#define VSZ   30522
#define DIM   768
#define KDELT 768
#define BOT   512
#define BATCH 256
#define MNEG  4096
#define EPSN  1e-6f
#define TEMPC 0.05f
#define INVT  20.0f

typedef _Float16 f16;
typedef _Float16 f16x8 __attribute__((ext_vector_type(8)));
typedef _Float16 f16x2 __attribute__((ext_vector_type(2)));
typedef float    f32x4 __attribute__((ext_vector_type(4)));

static __device__ __forceinline__ float gelu_exact(float x){
    return 0.5f * x * (1.0f + erff(x * 0.70710678118654752440f));
}
static __device__ __forceinline__ float softplus_f(float x){
    return fmaxf(x, 0.0f) + log1pf(expf(-fabsf(x)));
}

// ---------------------------------------------------------------------------
// fp16-MFMA GEMM, fp32 in/out. C = A[M,K(lda)] @ B.
// BSRC=0: B is [K][N] row-major (ldb=N stride) -> transpose-staged to LDS.
// BSRC=1: B is [N][K] row-major (A@B^T)        -> direct-staged.
// EPI=0: write split-K partial s into C + s*MN. EPI=1 (nsplit==1):
//        C = softplus(acc + bias[col]).
// Tile 128x128, BK=32, 256 threads (4 waves, each 64x64 = 4x4 16x16 frags).
// LDS [line][32k + pad8] so each lane's 8-k fragment is one ds_read_b128.
// ---------------------------------------------------------------------------
template<int BSRC, int NG, int EPI>
__global__ __launch_bounds__(256) void gemm16(
    const float* __restrict__ A, int lda,
    const float* __restrict__ B, int ldb,
    float* __restrict__ C, const float* __restrict__ bias,
    int N, int K, int nsplit, int MN)
{
    __shared__ f16 Al[128][40];
    __shared__ f16 Bl[128][40];
    const int t  = threadIdx.x;
    const int m0 = blockIdx.x * 128;
    const int n0 = blockIdx.y * 128;
    const int s  = blockIdx.z;
    const int kchunk = ((K + nsplit * 32 - 1) / (nsplit * 32)) * 32;
    const int kb = s * kchunk;
    const int ke = min(K, kb + kchunk);

    const int ar  = t >> 1;          // 0..127 (A/BT staging line)
    const int akh = (t & 1) * 16;    // k-half 0/16
    const int bn  = t & 127;         // B staging col (BSRC=0)
    const int bkh = (t >> 7) * 16;

    const int lane = t & 63, w = t >> 6;
    const int wr = (w >> 1) * 64, wc = (w & 1) * 64;
    const int fr = lane & 15, kg = (lane >> 4) * 8;

    f32x4 acc[4][4] = {};

    for (int k0 = kb; k0 < ke; k0 += 32) {
        const int krem = ke - k0;
        {   // ---- stage A tile [128][32] -> fp16 LDS
            const float* ap = A + (size_t)(m0 + ar) * lda + k0 + akh;
            f16x8 v0, v1;
            #pragma unroll
            for (int i = 0; i < 8; i++) {
                const int kk = akh + 2 * i;
                float x0 = 0.f, x1 = 0.f;
                if (kk + 1 < krem) { const float2 u = *(const float2*)(ap + 2 * i); x0 = u.x; x1 = u.y; }
                else if (kk < krem) { x0 = ap[2 * i]; }
                if (i < 4) { v0[2*i] = (f16)x0; v0[2*i+1] = (f16)x1; }
                else       { v1[2*(i-4)] = (f16)x0; v1[2*(i-4)+1] = (f16)x1; }
            }
            *(f16x8*)&Al[ar][akh]     = v0;
            *(f16x8*)&Al[ar][akh + 8] = v1;
        }
        if (BSRC == 0) {  // ---- stage B tile [32][128] transposed -> Bl[col][k]
            const bool nok = (!NG) || (n0 + bn < N);
            #pragma unroll
            for (int i = 0; i < 16; i += 2) {
                const int k1 = bkh + i;
                float x0 = 0.f, x1 = 0.f;
                if (nok) {
                    if (k1 < krem)     x0 = B[(size_t)(k0 + k1) * ldb + n0 + bn];
                    if (k1 + 1 < krem) x1 = B[(size_t)(k0 + k1 + 1) * ldb + n0 + bn];
                }
                f16x2 pv; pv[0] = (f16)x0; pv[1] = (f16)x1;
                *(f16x2*)&Bl[bn][k1] = pv;
            }
        } else {          // ---- stage B2 [N][K] rows directly
            const float* bp = B + (size_t)(n0 + ar) * ldb + k0 + akh;
            f16x8 v0, v1;
            #pragma unroll
            for (int i = 0; i < 8; i++) {
                const int kk = akh + 2 * i;
                float x0 = 0.f, x1 = 0.f;
                if (kk + 1 < krem) { const float2 u = *(const float2*)(bp + 2 * i); x0 = u.x; x1 = u.y; }
                else if (kk < krem) { x0 = bp[2 * i]; }
                if (i < 4) { v0[2*i] = (f16)x0; v0[2*i+1] = (f16)x1; }
                else       { v1[2*(i-4)] = (f16)x0; v1[2*(i-4)+1] = (f16)x1; }
            }
            *(f16x8*)&Bl[ar][akh]     = v0;
            *(f16x8*)&Bl[ar][akh + 8] = v1;
        }
        __syncthreads();
        f16x8 af[4], bf[4];
        #pragma unroll
        for (int m = 0; m < 4; m++) af[m] = *(const f16x8*)&Al[wr + m * 16 + fr][kg];
        #pragma unroll
        for (int n = 0; n < 4; n++) bf[n] = *(const f16x8*)&Bl[wc + n * 16 + fr][kg];
        #pragma unroll
        for (int m = 0; m < 4; m++)
            #pragma unroll
            for (int n = 0; n < 4; n++)
                acc[m][n] = __builtin_amdgcn_mfma_f32_16x16x32_f16(af[m], bf[n], acc[m][n], 0, 0, 0);
        __syncthreads();
    }

    float* Cp = (EPI == 0) ? (C + (size_t)s * MN) : C;
    #pragma unroll
    for (int m = 0; m < 4; m++) {
        #pragma unroll
        for (int n = 0; n < 4; n++) {
            #pragma unroll
            for (int j = 0; j < 4; j++) {
                const int row = m0 + wr + m * 16 + (lane >> 4) * 4 + j;
                const int col = n0 + wc + n * 16 + fr;
                if (NG && col >= N) continue;
                if (EPI == 0) Cp[(size_t)row * N + col] = acc[m][n][j];
                else          Cp[(size_t)row * N + col] = softplus_f(acc[m][n][j] + bias[col]);
            }
        }
    }
}

__global__ __launch_bounds__(256) void reduce_bias_gelu(
    const float* __restrict__ P, const float* __restrict__ bias,
    float* __restrict__ H, int M, int N, int nsplit)
{
    const int idx = blockIdx.x * 256 + threadIdx.x;
    if (idx >= M * N) return;
    const int n = idx % N;
    float s = 0.f;
    for (int k = 0; k < nsplit; k++) s += P[(size_t)k * M * N + idx];
    H[idx] = gelu_exact(s + bias[n]);
}

__global__ __launch_bounds__(256) void reduce_sum_parts(
    const float* __restrict__ P, float* __restrict__ Y, int MN, int nsplit)
{
    const int idx = blockIdx.x * 256 + threadIdx.x;
    if (idx >= MN) return;
    float s = 0.f;
    for (int k = 0; k < nsplit; k++) s += P[(size_t)k * MN + idx];
    Y[idx] = s;
}

// Per-row exact K-th-largest via 4-pass radix select on float bits (all >=0).
__global__ __launch_bounds__(256) void topk_thresh(
    const float* __restrict__ U, int N, int Kq, float* __restrict__ tout)
{
    __shared__ unsigned int hist[256];
    __shared__ unsigned int s_pref;
    __shared__ int s_rem;
    const int row = blockIdx.x, t = threadIdx.x;
    const float* u = U + (size_t)row * N;
    unsigned int pref = 0, pmask = 0;
    int remain = Kq;
    for (int pass = 0; pass < 4; pass++) {
        const int shift = 24 - 8 * pass;
        hist[t] = 0;
        __syncthreads();
        for (int j = t; j < N; j += 256) {
            const unsigned int v = __float_as_uint(u[j]);
            if ((v & pmask) == pref) atomicAdd(&hist[(v >> shift) & 0xFFu], 1u);
        }
        __syncthreads();
        if (t == 0) {
            unsigned int cum = 0; int b = 255;
            for (; b >= 0; b--) {
                const unsigned int h = hist[b];
                if (cum + h >= (unsigned int)remain) break;
                cum += h;
            }
            if (b < 0) b = 0;
            s_pref = pref | ((unsigned int)b << shift);
            s_rem  = remain - (int)cum;
        }
        __syncthreads();
        pref = s_pref; remain = s_rem;
        pmask |= (0xFFu << shift);
        __syncthreads();
    }
    if (t == 0) tout[row] = __uint_as_float(pref);
}

// U1 := clip(sr + dsp,0) - clip(dsm,0); row-sums of dsp/dsm for loss_sparse.
__global__ __launch_bounds__(256) void build_sq(
    float* __restrict__ U1, const float* __restrict__ U2,
    const float* __restrict__ sr,
    const float* __restrict__ tp, const float* __restrict__ tm,
    float* __restrict__ sparse_p, float* __restrict__ sparse_m)
{
    __shared__ float red[256];
    const int row = blockIdx.x, t = threadIdx.x;
    const float thp = tp[row], thm = tm[row];
    float* u1 = U1 + (size_t)row * VSZ;
    const float* u2 = U2 + (size_t)row * VSZ;
    const float* s  = sr + (size_t)row * VSZ;
    float sp = 0.f, sm = 0.f;
    for (int j = t; j < VSZ; j += 256) {
        const float up = u1[j], um = u2[j];
        const float dp = (up >= thp) ? up : 0.f;
        const float dm = (um >= thm) ? um : 0.f;
        sp += dp; sm += dm;
        u1[j] = fmaxf(s[j] + dp, 0.f) - fmaxf(dm, 0.f);
    }
    red[t] = sp; __syncthreads();
    for (int o = 128; o > 0; o >>= 1) { if (t < o) red[t] += red[t + o]; __syncthreads(); }
    if (t == 0) sparse_p[row] = red[0];
    __syncthreads();
    red[t] = sm; __syncthreads();
    for (int o = 128; o > 0; o >>= 1) { if (t < o) red[t] += red[t + o]; __syncthreads(); }
    if (t == 0) sparse_m[row] = red[0];
}

__global__ __launch_bounds__(256) void rownorm(
    const float* __restrict__ X, float* __restrict__ Y, int dbl)
{
    __shared__ float red[256];
    const int row = blockIdx.x, t = threadIdx.x;
    const float* x = X + (size_t)row * DIM;
    float* y = Y + (size_t)row * DIM;
    float v0 = x[t], v1 = x[t + 256], v2 = x[t + 512];
    red[t] = v0 * v0 + v1 * v1 + v2 * v2; __syncthreads();
    for (int o = 128; o > 0; o >>= 1) { if (t < o) red[t] += red[t + o]; __syncthreads(); }
    const float nrm = sqrtf(red[0]) + EPSN;
    v0 /= nrm; v1 /= nrm; v2 /= nrm;
    if (dbl) {
        __syncthreads();
        red[t] = v0 * v0 + v1 * v1 + v2 * v2; __syncthreads();
        for (int o = 128; o > 0; o >>= 1) { if (t < o) red[t] += red[t + o]; __syncthreads(); }
        const float n2 = sqrtf(red[0]) + EPSN;
        v0 /= n2; v1 /= n2; v2 /= n2;
    }
    y[t] = v0; y[t + 256] = v1; y[t + 512] = v2;
}

__global__ __launch_bounds__(256) void pos_dot(
    const float* __restrict__ zq, const float* __restrict__ zp,
    float* __restrict__ posL)
{
    __shared__ float red[256];
    const int row = blockIdx.x, t = threadIdx.x;
    const float* a = zq + (size_t)row * DIM;
    const float* b = zp + (size_t)row * DIM;
    red[t] = a[t] * b[t] + a[t + 256] * b[t + 256] + a[t + 512] * b[t + 512];
    __syncthreads();
    for (int o = 128; o > 0; o >>= 1) { if (t < o) red[t] += red[t + o]; __syncthreads(); }
    if (t == 0) posL[row] = red[0] / TEMPC;
}

// NegL holds raw dot products; scale by 1/TEMP here.
__global__ __launch_bounds__(256) void lse_loss(
    const float* __restrict__ negL, const float* __restrict__ posL,
    float* __restrict__ rowL)
{
    __shared__ float red[256];
    const int row = blockIdx.x, t = threadIdx.x;
    const float* nl = negL + (size_t)row * MNEG;
    const float p = posL[row];
    float lmax = (t == 0) ? p : -INFINITY;
    for (int j = t; j < MNEG; j += 256) lmax = fmaxf(lmax, nl[j] * INVT);
    red[t] = lmax; __syncthreads();
    for (int o = 128; o > 0; o >>= 1) { if (t < o) red[t] = fmaxf(red[t], red[t + o]); __syncthreads(); }
    const float mx = red[0];
    __syncthreads();
    float lsum = (t == 0) ? expf(p - mx) : 0.f;
    for (int j = t; j < MNEG; j += 256) lsum += expf(nl[j] * INVT - mx);
    red[t] = lsum; __syncthreads();
    for (int o = 128; o > 0; o >>= 1) { if (t < o) red[t] += red[t + o]; __syncthreads(); }
    if (t == 0) rowL[row] = mx + logf(red[0]) - p;
}

__global__ __launch_bounds__(256) void rec_row(
    const float* __restrict__ zhat, const float* __restrict__ zrn,
    float* __restrict__ part)
{
    __shared__ float red[256];
    const int row = blockIdx.x, t = threadIdx.x;
    const float* a = zhat + (size_t)row * DIM;
    const float* b = zrn + (size_t)row * DIM;
    const float d0 = a[t] - b[t], d1 = a[t + 256] - b[t + 256], d2 = a[t + 512] - b[t + 512];
    red[t] = d0 * d0 + d1 * d1 + d2 * d2;
    __syncthreads();
    for (int o = 128; o > 0; o >>= 1) { if (t < o) red[t] += red[t + o]; __syncthreads(); }
    if (t == 0) part[row] = red[0];
}

__global__ __launch_bounds__(256) void final_combine(
    const float* __restrict__ rowL, const float* __restrict__ recP,
    const float* __restrict__ spP, const float* __restrict__ spM,
    float* __restrict__ out)
{
    __shared__ float red[256];
    const int t = threadIdx.x;
    red[t] = rowL[t]; __syncthreads();
    for (int o = 128; o > 0; o >>= 1) { if (t < o) red[t] += red[t + o]; __syncthreads(); }
    const float retr = red[0] / 256.0f;
    __syncthreads();
    red[t] = recP[t]; __syncthreads();
    for (int o = 128; o > 0; o >>= 1) { if (t < o) red[t] += red[t + o]; __syncthreads(); }
    const float rec = red[0] / (float)(BATCH * DIM);
    __syncthreads();
    red[t] = spP[t] + spM[t]; __syncthreads();
    for (int o = 128; o > 0; o >>= 1) { if (t < o) red[t] += red[t + o]; __syncthreads(); }
    const float sparse = red[0] / 256.0f;
    if (t == 0) out[0] = retr + 1.0f * rec + 1e-4f * sparse;
}

extern "C" void kernel_launch(void* const* d_in, const int* in_sizes, int n_in,
                              void* d_out, int out_size, void* d_ws, size_t ws_size,
                              hipStream_t stream)
{
    const float* ht   = (const float*)d_in[0];
    const float* sr   = (const float*)d_in[1];
    const float* zpos = (const float*)d_in[2];
    const float* zneg = (const float*)d_in[3];
    const float* zr   = (const float*)d_in[4];
    const float* W1p  = (const float*)d_in[5];
    const float* b1p  = (const float*)d_in[6];
    const float* W2p  = (const float*)d_in[7];
    const float* b2p  = (const float*)d_in[8];
    const float* W1m  = (const float*)d_in[9];
    const float* b1m  = (const float*)d_in[10];
    const float* W2m  = (const float*)d_in[11];
    const float* b2m  = (const float*)d_in[12];
    const float* Wdec = (const float*)d_in[13];
    float* out = (float*)d_out;

    // workspace layout (bytes). U2 region is reused after build_sq for the
    // normalization outputs + NegL (all stream-ordered).
    char* ws = (char*)d_ws;
    float* U1   = (float*)(ws + 0);            // 31,254,528
    float* U2   = (float*)(ws + 31254528);     // 31,254,528
    float* Zn   = (float*)(ws + 31254528);     //   12,582,912 (alias, post build_sq)
    float* Zp   = (float*)(ws + 43837440);     //      786,432
    float* Zrn  = (float*)(ws + 44623872);     //      786,432
    float* NegL = (float*)(ws + 45410304);     //    4,194,304
    float* P    = (float*)(ws + 62509056);     // 16,777,216 (split-K partials, serial reuse)
    float* Hp   = (float*)(ws + 79286272);     //      524,288
    float* Hm   = (float*)(ws + 79810560);     //      524,288
    float* Y1   = (float*)(ws + 80334848);     //      786,432
    float* Y2   = (float*)(ws + 81121280);     //      786,432
    float* tP   = (float*)(ws + 81907712);     // small vectors (256 floats each)
    float* tM   = tP + 256;
    float* spP  = tP + 512;
    float* spM  = tP + 768;
    float* posL = tP + 1024;
    float* rowL = tP + 1280;
    float* recP = tP + 1536;
    (void)in_sizes; (void)n_in; (void)out_size; (void)ws_size;

    const dim3 blk(256);

    // ---- GEMM1 (ht @ W1, K=30522, split-K 32) + bias/GELU reduce
    gemm16<0,0,0><<<dim3(2,4,32), blk, 0, stream>>>(ht, VSZ, W1p, BOT, P, nullptr, BOT, VSZ, 32, BATCH*BOT);
    reduce_bias_gelu<<<dim3(512), blk, 0, stream>>>(P, b1p, Hp, BATCH, BOT, 32);
    gemm16<0,0,0><<<dim3(2,4,32), blk, 0, stream>>>(ht, VSZ, W1m, BOT, P, nullptr, BOT, VSZ, 32, BATCH*BOT);
    reduce_bias_gelu<<<dim3(512), blk, 0, stream>>>(P, b1m, Hm, BATCH, BOT, 32);

    // ---- GEMM2 (h @ W2, N=30522) with fused softplus+bias epilogue
    gemm16<0,1,1><<<dim3(2,239,1), blk, 0, stream>>>(Hp, BOT, W2p, VSZ, U1, b2p, VSZ, BOT, 1, 0);
    gemm16<0,1,1><<<dim3(2,239,1), blk, 0, stream>>>(Hm, BOT, W2m, VSZ, U2, b2m, VSZ, BOT, 1, 0);

    // ---- exact top-K thresholds, then sq build + sparse row sums
    topk_thresh<<<dim3(256), blk, 0, stream>>>(U1, VSZ, KDELT, tP);
    topk_thresh<<<dim3(256), blk, 0, stream>>>(U2, VSZ, KDELT, tM);
    build_sq<<<dim3(256), blk, 0, stream>>>(U1, U2, sr, tP, tM, spP, spM);

    // ---- decode GEMMs (K=30522, split-K 16)
    gemm16<0,0,0><<<dim3(2,6,16), blk, 0, stream>>>(U1, VSZ, Wdec, DIM, P, nullptr, DIM, VSZ, 16, BATCH*DIM);
    reduce_sum_parts<<<dim3(768), blk, 0, stream>>>(P, Y1, BATCH*DIM, 16);
    gemm16<0,0,0><<<dim3(2,6,16), blk, 0, stream>>>(sr, VSZ, Wdec, DIM, P, nullptr, DIM, VSZ, 16, BATCH*DIM);
    reduce_sum_parts<<<dim3(768), blk, 0, stream>>>(P, Y2, BATCH*DIM, 16);

    // ---- normalizations
    rownorm<<<dim3(256),  blk, 0, stream>>>(Y1, Y1, 1);   // zq (double norm)
    rownorm<<<dim3(256),  blk, 0, stream>>>(Y2, Y2, 0);   // zhat_r
    rownorm<<<dim3(4096), blk, 0, stream>>>(zneg, Zn, 0);
    rownorm<<<dim3(256),  blk, 0, stream>>>(zpos, Zp, 0);
    rownorm<<<dim3(256),  blk, 0, stream>>>(zr,   Zrn, 0);

    // ---- retrieval loss
    pos_dot<<<dim3(256), blk, 0, stream>>>(Y1, Zp, posL);
    gemm16<1,0,0><<<dim3(2,32,4), blk, 0, stream>>>(Y1, DIM, Zn, DIM, P, nullptr, MNEG, DIM, 4, BATCH*MNEG);
    reduce_sum_parts<<<dim3(4096), blk, 0, stream>>>(P, NegL, BATCH*MNEG, 4);
    lse_loss<<<dim3(256), blk, 0, stream>>>(NegL, posL, rowL);

    // ---- reconstruction loss
    rec_row<<<dim3(256), blk, 0, stream>>>(Y2, Zrn, recP);

    // ---- combine
    final_combine<<<dim3(1), blk, 0, stream>>>(rowL, recP, spP, spM, out);
}

// Round 3
// 1516.879 us; speedup vs baseline: 1.5235x; 1.5231x over previous
//
#include <hip/hip_runtime.h>
#include <math.h>

#define VSZ   30522
#define DIM   768
#define KDELT 768
#define BOT   512
#define BATCH 256
#define MNEG  4096
#define EPSN  1e-6f
#define TEMPC 0.05f
#define INVT  20.0f

typedef _Float16 f16;
typedef _Float16 f16x8 __attribute__((ext_vector_type(8)));
typedef _Float16 f16x2 __attribute__((ext_vector_type(2)));
typedef float    f32x4 __attribute__((ext_vector_type(4)));

static __device__ __forceinline__ float gelu_exact(float x){
    return 0.5f * x * (1.0f + erff(x * 0.70710678118654752440f));
}
static __device__ __forceinline__ float softplus_f(float x){
    return fmaxf(x, 0.0f) + log1pf(expf(-fabsf(x)));
}

// ---------------------------------------------------------------------------
// fp32-in / fp16-MFMA GEMM with coalesced staging and dual-branch z-fusion.
//   branch = blockIdx.z / nsplit selects {A,B,C,bias} set (p/m or sq/sr).
// BSRC=0: B is [K][N] (ldb=N) -> transpose-staged (lane-per-n, coalesced).
// BSRC=1: B is [N][K] (ldb=K) -> row-staged like A.
// EPI=0: C[s*MN + ...] = partial.  EPI=1 (nsplit==1): C = softplus(acc+bias).
// Tile 128x128, BK=32, 256 threads, 4 waves each 64x64 (4x4 16x16x32 frags).
// ---------------------------------------------------------------------------
template<int BSRC, int NG, int EPI>
__global__ __launch_bounds__(256) void gemm32t(
    const float* __restrict__ A0, const float* __restrict__ A1, int lda,
    const float* __restrict__ B0, const float* __restrict__ B1, int ldb,
    float* __restrict__ C0, float* __restrict__ C1,
    const float* __restrict__ bias0, const float* __restrict__ bias1,
    int N, int K, int nsplit, int MN)
{
    __shared__ f16 Al[128][40];
    __shared__ f16 Bl[128][40];
    const int t  = threadIdx.x;
    const int m0 = blockIdx.x * 128;
    const int n0 = blockIdx.y * 128;
    const int br = blockIdx.z / nsplit;
    const int s  = blockIdx.z % nsplit;
    const float* __restrict__ A = br ? A1 : A0;
    const float* __restrict__ B = br ? B1 : B0;
    float* __restrict__ C       = br ? C1 : C0;
    const float* __restrict__ bias = br ? bias1 : bias0;

    const int kchunk = ((K + nsplit * 32 - 1) / (nsplit * 32)) * 32;
    const int kb = s * kchunk;
    const int ke = min(K, kb + kchunk);

    const int sr_ = t >> 4;          // staging row-in-pass 0..15
    const int sc  = (t & 15) * 2;    // staging col pair 0..30
    const int bn  = t & 127;         // B transpose staging n
    const int bk  = t >> 7;          // 0..1

    const int lane = t & 63, w = t >> 6;
    const int wr = (w >> 1) * 64, wc = (w & 1) * 64;
    const int fr = lane & 15, kg = (lane >> 4) * 8;

    f32x4 acc[4][4] = {};

    for (int k0 = kb; k0 < ke; k0 += 32) {
        const int krem = min(32, ke - k0);   // even always
        // ---- A tile [128][32]: 8 passes x 16 rows, float2 coalesced
        #pragma unroll
        for (int p = 0; p < 8; p++) {
            const int row = p * 16 + sr_;
            float2 u = {0.f, 0.f};
            if (sc < krem) u = *(const float2*)(A + (size_t)(m0 + row) * lda + k0 + sc);
            f16x2 v; v[0] = (f16)u.x; v[1] = (f16)u.y;
            *(f16x2*)&Al[row][sc] = v;
        }
        if (BSRC == 0) {
            // ---- B tile [32][128] -> Bl[n][k]; lane-per-n coalesced reads
            #pragma unroll
            for (int p = 0; p < 16; p++) {
                const int kk = p * 2 + bk;
                float x = 0.f;
                if (kk < krem && (!NG || n0 + bn < N))
                    x = B[(size_t)(k0 + kk) * ldb + n0 + bn];
                Bl[bn][kk] = (f16)x;
            }
        } else {
            // ---- B2 rows [n][k] staged like A
            #pragma unroll
            for (int p = 0; p < 8; p++) {
                const int row = p * 16 + sr_;
                float2 u = {0.f, 0.f};
                if (sc < krem && (!NG || n0 + row < N))
                    u = *(const float2*)(B + (size_t)(n0 + row) * ldb + k0 + sc);
                f16x2 v; v[0] = (f16)u.x; v[1] = (f16)u.y;
                *(f16x2*)&Bl[row][sc] = v;
            }
        }
        __syncthreads();
        f16x8 af[4], bf[4];
        #pragma unroll
        for (int m = 0; m < 4; m++) af[m] = *(const f16x8*)&Al[wr + m * 16 + fr][kg];
        #pragma unroll
        for (int n = 0; n < 4; n++) bf[n] = *(const f16x8*)&Bl[wc + n * 16 + fr][kg];
        #pragma unroll
        for (int m = 0; m < 4; m++)
            #pragma unroll
            for (int n = 0; n < 4; n++)
                acc[m][n] = __builtin_amdgcn_mfma_f32_16x16x32_f16(af[m], bf[n], acc[m][n], 0, 0, 0);
        __syncthreads();
    }

    float* Cp = (EPI == 0) ? (C + (size_t)s * MN) : C;
    #pragma unroll
    for (int m = 0; m < 4; m++) {
        #pragma unroll
        for (int n = 0; n < 4; n++) {
            #pragma unroll
            for (int j = 0; j < 4; j++) {
                const int row = m0 + wr + m * 16 + (lane >> 4) * 4 + j;
                const int col = n0 + wc + n * 16 + fr;
                if (NG && col >= N) continue;
                if (EPI == 0) Cp[(size_t)row * N + col] = acc[m][n][j];
                else          Cp[(size_t)row * N + col] = softplus_f(acc[m][n][j] + bias[col]);
            }
        }
    }
}

__global__ __launch_bounds__(256) void reduce_bias_gelu(
    const float* __restrict__ P, const float* __restrict__ bias,
    float* __restrict__ H, int M, int N, int nsplit)
{
    const int idx = blockIdx.x * 256 + threadIdx.x;
    if (idx >= M * N) return;
    const int n = idx % N;
    float s = 0.f;
    for (int k = 0; k < nsplit; k++) s += P[(size_t)k * M * N + idx];
    H[idx] = gelu_exact(s + bias[n]);
}

__global__ __launch_bounds__(256) void reduce_sum_parts(
    const float* __restrict__ P, float* __restrict__ Y, int MN, int nsplit)
{
    const int idx = blockIdx.x * 256 + threadIdx.x;
    if (idx >= MN) return;
    float s = 0.f;
    for (int k = 0; k < nsplit; k++) s += P[(size_t)k * MN + idx];
    Y[idx] = s;
}

// Per-row exact K-th-largest via 4-pass radix select on float bits (all >=0).
__global__ __launch_bounds__(256) void topk_thresh(
    const float* __restrict__ U, int N, int Kq, float* __restrict__ tout)
{
    __shared__ unsigned int hist[256];
    __shared__ unsigned int s_pref;
    __shared__ int s_rem;
    const int row = blockIdx.x, t = threadIdx.x;
    const float* u = U + (size_t)row * N;
    unsigned int pref = 0, pmask = 0;
    int remain = Kq;
    for (int pass = 0; pass < 4; pass++) {
        const int shift = 24 - 8 * pass;
        hist[t] = 0;
        __syncthreads();
        for (int j = t; j < N; j += 256) {
            const unsigned int v = __float_as_uint(u[j]);
            if ((v & pmask) == pref) atomicAdd(&hist[(v >> shift) & 0xFFu], 1u);
        }
        __syncthreads();
        if (t == 0) {
            unsigned int cum = 0; int b = 255;
            for (; b >= 0; b--) {
                const unsigned int h = hist[b];
                if (cum + h >= (unsigned int)remain) break;
                cum += h;
            }
            if (b < 0) b = 0;
            s_pref = pref | ((unsigned int)b << shift);
            s_rem  = remain - (int)cum;
        }
        __syncthreads();
        pref = s_pref; remain = s_rem;
        pmask |= (0xFFu << shift);
        __syncthreads();
    }
    if (t == 0) tout[row] = __uint_as_float(pref);
}

// U1 := clip(sr + dsp,0) - clip(dsm,0); row-sums of dsp/dsm for loss_sparse.
__global__ __launch_bounds__(256) void build_sq(
    float* __restrict__ U1, const float* __restrict__ U2,
    const float* __restrict__ sr,
    const float* __restrict__ tp, const float* __restrict__ tm,
    float* __restrict__ sparse_p, float* __restrict__ sparse_m)
{
    __shared__ float red[256];
    const int row = blockIdx.x, t = threadIdx.x;
    const float thp = tp[row], thm = tm[row];
    float* u1 = U1 + (size_t)row * VSZ;
    const float* u2 = U2 + (size_t)row * VSZ;
    const float* s  = sr + (size_t)row * VSZ;
    float sp = 0.f, sm = 0.f;
    for (int j = t; j < VSZ; j += 256) {
        const float up = u1[j], um = u2[j];
        const float dp = (up >= thp) ? up : 0.f;
        const float dm = (um >= thm) ? um : 0.f;
        sp += dp; sm += dm;
        u1[j] = fmaxf(s[j] + dp, 0.f) - fmaxf(dm, 0.f);
    }
    red[t] = sp; __syncthreads();
    for (int o = 128; o > 0; o >>= 1) { if (t < o) red[t] += red[t + o]; __syncthreads(); }
    if (t == 0) sparse_p[row] = red[0];
    __syncthreads();
    red[t] = sm; __syncthreads();
    for (int o = 128; o > 0; o >>= 1) { if (t < o) red[t] += red[t + o]; __syncthreads(); }
    if (t == 0) sparse_m[row] = red[0];
}

__global__ __launch_bounds__(256) void rownorm(
    const float* __restrict__ X, float* __restrict__ Y, int dbl)
{
    __shared__ float red[256];
    const int row = blockIdx.x, t = threadIdx.x;
    const float* x = X + (size_t)row * DIM;
    float* y = Y + (size_t)row * DIM;
    float v0 = x[t], v1 = x[t + 256], v2 = x[t + 512];
    red[t] = v0 * v0 + v1 * v1 + v2 * v2; __syncthreads();
    for (int o = 128; o > 0; o >>= 1) { if (t < o) red[t] += red[t + o]; __syncthreads(); }
    const float nrm = sqrtf(red[0]) + EPSN;
    v0 /= nrm; v1 /= nrm; v2 /= nrm;
    if (dbl) {
        __syncthreads();
        red[t] = v0 * v0 + v1 * v1 + v2 * v2; __syncthreads();
        for (int o = 128; o > 0; o >>= 1) { if (t < o) red[t] += red[t + o]; __syncthreads(); }
        const float n2 = sqrtf(red[0]) + EPSN;
        v0 /= n2; v1 /= n2; v2 /= n2;
    }
    y[t] = v0; y[t + 256] = v1; y[t + 512] = v2;
}

__global__ __launch_bounds__(256) void pos_dot(
    const float* __restrict__ zq, const float* __restrict__ zp,
    float* __restrict__ posL)
{
    __shared__ float red[256];
    const int row = blockIdx.x, t = threadIdx.x;
    const float* a = zq + (size_t)row * DIM;
    const float* b = zp + (size_t)row * DIM;
    red[t] = a[t] * b[t] + a[t + 256] * b[t + 256] + a[t + 512] * b[t + 512];
    __syncthreads();
    for (int o = 128; o > 0; o >>= 1) { if (t < o) red[t] += red[t + o]; __syncthreads(); }
    if (t == 0) posL[row] = red[0] / TEMPC;
}

// NegL holds raw dot products; scale by 1/TEMP here.
__global__ __launch_bounds__(256) void lse_loss(
    const float* __restrict__ negL, const float* __restrict__ posL,
    float* __restrict__ rowL)
{
    __shared__ float red[256];
    const int row = blockIdx.x, t = threadIdx.x;
    const float* nl = negL + (size_t)row * MNEG;
    const float p = posL[row];
    float lmax = (t == 0) ? p : -INFINITY;
    for (int j = t; j < MNEG; j += 256) lmax = fmaxf(lmax, nl[j] * INVT);
    red[t] = lmax; __syncthreads();
    for (int o = 128; o > 0; o >>= 1) { if (t < o) red[t] = fmaxf(red[t], red[t + o]); __syncthreads(); }
    const float mx = red[0];
    __syncthreads();
    float lsum = (t == 0) ? expf(p - mx) : 0.f;
    for (int j = t; j < MNEG; j += 256) lsum += expf(nl[j] * INVT - mx);
    red[t] = lsum; __syncthreads();
    for (int o = 128; o > 0; o >>= 1) { if (t < o) red[t] += red[t + o]; __syncthreads(); }
    if (t == 0) rowL[row] = mx + logf(red[0]) - p;
}

__global__ __launch_bounds__(256) void rec_row(
    const float* __restrict__ zhat, const float* __restrict__ zrn,
    float* __restrict__ part)
{
    __shared__ float red[256];
    const int row = blockIdx.x, t = threadIdx.x;
    const float* a = zhat + (size_t)row * DIM;
    const float* b = zrn + (size_t)row * DIM;
    const float d0 = a[t] - b[t], d1 = a[t + 256] - b[t + 256], d2 = a[t + 512] - b[t + 512];
    red[t] = d0 * d0 + d1 * d1 + d2 * d2;
    __syncthreads();
    for (int o = 128; o > 0; o >>= 1) { if (t < o) red[t] += red[t + o]; __syncthreads(); }
    if (t == 0) part[row] = red[0];
}

__global__ __launch_bounds__(256) void final_combine(
    const float* __restrict__ rowL, const float* __restrict__ recP,
    const float* __restrict__ spP, const float* __restrict__ spM,
    float* __restrict__ out)
{
    __shared__ float red[256];
    const int t = threadIdx.x;
    red[t] = rowL[t]; __syncthreads();
    for (int o = 128; o > 0; o >>= 1) { if (t < o) red[t] += red[t + o]; __syncthreads(); }
    const float retr = red[0] / 256.0f;
    __syncthreads();
    red[t] = recP[t]; __syncthreads();
    for (int o = 128; o > 0; o >>= 1) { if (t < o) red[t] += red[t + o]; __syncthreads(); }
    const float rec = red[0] / (float)(BATCH * DIM);
    __syncthreads();
    red[t] = spP[t] + spM[t]; __syncthreads();
    for (int o = 128; o > 0; o >>= 1) { if (t < o) red[t] += red[t + o]; __syncthreads(); }
    const float sparse = red[0] / 256.0f;
    if (t == 0) out[0] = retr + 1.0f * rec + 1e-4f * sparse;
}

extern "C" void kernel_launch(void* const* d_in, const int* in_sizes, int n_in,
                              void* d_out, int out_size, void* d_ws, size_t ws_size,
                              hipStream_t stream)
{
    const float* ht   = (const float*)d_in[0];
    const float* sr   = (const float*)d_in[1];
    const float* zpos = (const float*)d_in[2];
    const float* zneg = (const float*)d_in[3];
    const float* zr   = (const float*)d_in[4];
    const float* W1p  = (const float*)d_in[5];
    const float* b1p  = (const float*)d_in[6];
    const float* W2p  = (const float*)d_in[7];
    const float* b2p  = (const float*)d_in[8];
    const float* W1m  = (const float*)d_in[9];
    const float* b1m  = (const float*)d_in[10];
    const float* W2m  = (const float*)d_in[11];
    const float* b2m  = (const float*)d_in[12];
    const float* Wdec = (const float*)d_in[13];
    float* out = (float*)d_out;

    // workspace layout (bytes)
    char* ws = (char*)d_ws;
    float* U1   = (float*)(ws + 0);            // 31,254,528
    float* U2   = (float*)(ws + 31254528);     // 31,254,528
    float* P    = (float*)(ws + 62509056);     // 33,554,432 partial arena (serial reuse)
    float* P1g  = (float*)(ws + 62509056 + 16777216);  // gemm1 branch-m partials
    float* P1d  = (float*)(ws + 62509056 + 12582912);  // decode branch-sr partials
    float* Hp   = (float*)(ws + 96063488);     //      524,288
    float* Hm   = (float*)(ws + 96587776);     //      524,288
    float* Y1   = (float*)(ws + 97112064);     //      786,432
    float* Y2   = (float*)(ws + 97898496);     //      786,432
    float* Zn   = (float*)(ws + 98684928);     //   12,582,912
    float* Zp   = (float*)(ws + 111267840);    //      786,432
    float* Zrn  = (float*)(ws + 112054272);    //      786,432
    float* NegL = (float*)(ws + 112840704);    //    4,194,304
    float* tP   = (float*)(ws + 117035008);    // small vectors (256 floats each)
    float* tM   = tP + 256;
    float* spP  = tP + 512;
    float* spM  = tP + 768;
    float* posL = tP + 1024;
    float* rowL = tP + 1280;
    float* recP = tP + 1536;
    (void)in_sizes; (void)n_in; (void)out_size; (void)ws_size;

    const dim3 blk(256);

    // ---- GEMM1 dual (ht@W1p | ht@W1m), split-K 32 each, grid 512 blocks
    gemm32t<0,0,0><<<dim3(2,4,64), blk, 0, stream>>>(
        ht, ht, VSZ, W1p, W1m, BOT, P, P1g, nullptr, nullptr,
        BOT, VSZ, 32, BATCH*BOT);
    reduce_bias_gelu<<<dim3(512), blk, 0, stream>>>(P,   b1p, Hp, BATCH, BOT, 32);
    reduce_bias_gelu<<<dim3(512), blk, 0, stream>>>(P1g, b1m, Hm, BATCH, BOT, 32);

    // ---- GEMM2 dual (Hp@W2p | Hm@W2m), fused softplus+bias, grid 956 blocks
    gemm32t<0,1,1><<<dim3(2,239,2), blk, 0, stream>>>(
        Hp, Hm, BOT, W2p, W2m, VSZ, U1, U2, b2p, b2m,
        VSZ, BOT, 1, 0);

    // ---- exact top-K thresholds, then sq build + sparse row sums
    topk_thresh<<<dim3(256), blk, 0, stream>>>(U1, VSZ, KDELT, tP);
    topk_thresh<<<dim3(256), blk, 0, stream>>>(U2, VSZ, KDELT, tM);
    build_sq<<<dim3(256), blk, 0, stream>>>(U1, U2, sr, tP, tM, spP, spM);

    // ---- decode dual (sq@Wdec | sr@Wdec), split-K 16, grid 384 blocks
    gemm32t<0,0,0><<<dim3(2,6,32), blk, 0, stream>>>(
        U1, sr, VSZ, Wdec, Wdec, DIM, P, P1d, nullptr, nullptr,
        DIM, VSZ, 16, BATCH*DIM);
    reduce_sum_parts<<<dim3(768), blk, 0, stream>>>(P,   Y1, BATCH*DIM, 16);
    reduce_sum_parts<<<dim3(768), blk, 0, stream>>>(P1d, Y2, BATCH*DIM, 16);

    // ---- normalizations
    rownorm<<<dim3(256),  blk, 0, stream>>>(Y1, Y1, 1);   // zq (double norm)
    rownorm<<<dim3(256),  blk, 0, stream>>>(Y2, Y2, 0);   // zhat_r
    rownorm<<<dim3(4096), blk, 0, stream>>>(zneg, Zn, 0);
    rownorm<<<dim3(256),  blk, 0, stream>>>(zpos, Zp, 0);
    rownorm<<<dim3(256),  blk, 0, stream>>>(zr,   Zrn, 0);

    // ---- retrieval loss
    pos_dot<<<dim3(256), blk, 0, stream>>>(Y1, Zp, posL);
    gemm32t<1,0,0><<<dim3(2,32,4), blk, 0, stream>>>(
        Y1, Y1, DIM, Zn, Zn, DIM, P, P, nullptr, nullptr,
        MNEG, DIM, 4, BATCH*MNEG);
    reduce_sum_parts<<<dim3(4096), blk, 0, stream>>>(P, NegL, BATCH*MNEG, 4);
    lse_loss<<<dim3(256), blk, 0, stream>>>(NegL, posL, rowL);

    // ---- reconstruction loss
    rec_row<<<dim3(256), blk, 0, stream>>>(Y2, Zrn, recP);

    // ---- combine
    final_combine<<<dim3(1), blk, 0, stream>>>(rowL, recP, spP, spM, out);
}

// Round 4
// 729.681 us; speedup vs baseline: 3.1672x; 2.0788x over previous
//
#include <hip/hip_runtime.h>
#include <math.h>

#define VSZ   30522
#define DIM   768
#define KDELT 768
#define BOT   512
#define BATCH 256
#define MNEG  4096
#define EPSN  1e-6f
#define TEMPC 0.05f
#define INVT  20.0f

typedef _Float16 f16;
typedef _Float16 f16x8 __attribute__((ext_vector_type(8)));
typedef _Float16 f16x2 __attribute__((ext_vector_type(2)));
typedef float    f32x4 __attribute__((ext_vector_type(4)));

static __device__ __forceinline__ float gelu_exact(float x){
    return 0.5f * x * (1.0f + erff(x * 0.70710678118654752440f));
}
static __device__ __forceinline__ float softplus_f(float x){
    return fmaxf(x, 0.0f) + log1pf(expf(-fabsf(x)));
}

// ---------------------------------------------------------------------------
// fp32-in / fp16-MFMA GEMM, register-batched staging + next-tile prefetch
// (T14): loads for tile k+1 are issued before tile k's MFMAs so HBM latency
// hides under compute. __launch_bounds__(256,2) gives the register budget
// (~256) needed to keep ~24 loads/thread in flight — at the default budget
// the compiler serialized staging (VGPR_Count=68, 9.8k cyc/K-step measured).
//   branch = blockIdx.z / nsplit selects {A,B,C,bias} set (p/m or sq/sr).
// BSRC=0: B is [K][N] (ldb=N) -> transpose-staged. BSRC=1: B is [N][K].
// EPI=0: C[s*MN+..] = partial. EPI=1 (nsplit==1): C = softplus(acc+bias).
// Tile 128x128, BK=32, 256 threads, 4 waves each 64x64 (4x4 16x16x32 frags).
// ---------------------------------------------------------------------------
template<int BSRC, int NG, int EPI>
__global__ __launch_bounds__(256, 2) void gemm32t(
    const float* __restrict__ A0, const float* __restrict__ A1, int lda,
    const float* __restrict__ B0, const float* __restrict__ B1, int ldb,
    float* __restrict__ C0, float* __restrict__ C1,
    const float* __restrict__ bias0, const float* __restrict__ bias1,
    int N, int K, int nsplit, int MN)
{
    __shared__ f16 Al[128][40];
    __shared__ f16 Bl[128][40];
    const int t  = threadIdx.x;
    const int m0 = blockIdx.x * 128;
    const int n0 = blockIdx.y * 128;
    const int br = blockIdx.z / nsplit;
    const int s  = blockIdx.z % nsplit;
    const float* __restrict__ A = br ? A1 : A0;
    const float* __restrict__ B = br ? B1 : B0;
    float* __restrict__ C       = br ? C1 : C0;
    const float* __restrict__ bias = br ? bias1 : bias0;

    const int kchunk = ((K + nsplit * 32 - 1) / (nsplit * 32)) * 32;
    const int kb = s * kchunk;
    const int ke = min(K, kb + kchunk);

    const int sr_ = t >> 4;          // staging row-in-pass 0..15
    const int sc  = (t & 15) * 2;    // staging col pair 0..30
    const int bn  = t & 127;         // B transpose staging n
    const int bk  = t >> 7;          // 0..1

    const int lane = t & 63, w = t >> 6;
    const int wr = (w >> 1) * 64, wc = (w & 1) * 64;
    const int fr = lane & 15, kg = (lane >> 4) * 8;

    f32x4 acc[4][4] = {};

    float2 ra[8];
    float  rb[16];
    float2 rb2[8];

    auto loadA = [&](int k0, int krem) {
        #pragma unroll
        for (int p = 0; p < 8; p++) {
            const int row = p * 16 + sr_;
            float2 u = {0.f, 0.f};
            if (sc < krem) u = *(const float2*)(A + (size_t)(m0 + row) * lda + k0 + sc);
            ra[p] = u;
        }
    };
    auto loadB = [&](int k0, int krem) {
        if (BSRC == 0) {
            const bool nok = (!NG) || (n0 + bn < N);
            #pragma unroll
            for (int p = 0; p < 16; p++) {
                const int kk = p * 2 + bk;
                float x = 0.f;
                if (kk < krem && nok) x = B[(size_t)(k0 + kk) * ldb + n0 + bn];
                rb[p] = x;
            }
        } else {
            #pragma unroll
            for (int p = 0; p < 8; p++) {
                const int row = p * 16 + sr_;
                float2 u = {0.f, 0.f};
                if (sc < krem) u = *(const float2*)(B + (size_t)(n0 + row) * ldb + k0 + sc);
                rb2[p] = u;
            }
        }
    };
    auto storeA = [&]() {
        #pragma unroll
        for (int p = 0; p < 8; p++) {
            f16x2 v; v[0] = (f16)ra[p].x; v[1] = (f16)ra[p].y;
            *(f16x2*)&Al[p * 16 + sr_][sc] = v;
        }
    };
    auto storeB = [&]() {
        if (BSRC == 0) {
            #pragma unroll
            for (int p = 0; p < 16; p++)
                Bl[bn][p * 2 + bk] = (f16)rb[p];
        } else {
            #pragma unroll
            for (int p = 0; p < 8; p++) {
                f16x2 v; v[0] = (f16)rb2[p].x; v[1] = (f16)rb2[p].y;
                *(f16x2*)&Bl[p * 16 + sr_][sc] = v;
            }
        }
    };

    int k0 = kb;
    {
        const int kr = min(32, ke - k0);
        loadA(k0, kr); loadB(k0, kr);
    }
    while (k0 < ke) {
        storeA(); storeB();
        __syncthreads();
        const int k1 = k0 + 32;
        if (k1 < ke) {                       // prefetch next tile into regs
            const int kr = min(32, ke - k1);
            loadA(k1, kr); loadB(k1, kr);
        }
        f16x8 af[4], bf[4];
        #pragma unroll
        for (int m = 0; m < 4; m++) af[m] = *(const f16x8*)&Al[wr + m * 16 + fr][kg];
        #pragma unroll
        for (int n = 0; n < 4; n++) bf[n] = *(const f16x8*)&Bl[wc + n * 16 + fr][kg];
        #pragma unroll
        for (int m = 0; m < 4; m++)
            #pragma unroll
            for (int n = 0; n < 4; n++)
                acc[m][n] = __builtin_amdgcn_mfma_f32_16x16x32_f16(af[m], bf[n], acc[m][n], 0, 0, 0);
        __syncthreads();
        k0 = k1;
    }

    float* Cp = (EPI == 0) ? (C + (size_t)s * MN) : C;
    #pragma unroll
    for (int m = 0; m < 4; m++) {
        #pragma unroll
        for (int n = 0; n < 4; n++) {
            #pragma unroll
            for (int j = 0; j < 4; j++) {
                const int row = m0 + wr + m * 16 + (lane >> 4) * 4 + j;
                const int col = n0 + wc + n * 16 + fr;
                if (NG && col >= N) continue;
                if (EPI == 0) Cp[(size_t)row * N + col] = acc[m][n][j];
                else          Cp[(size_t)row * N + col] = softplus_f(acc[m][n][j] + bias[col]);
            }
        }
    }
}

__global__ __launch_bounds__(256) void reduce_bias_gelu(
    const float* __restrict__ P, const float* __restrict__ bias,
    float* __restrict__ H, int M, int N, int nsplit)
{
    const int idx = blockIdx.x * 256 + threadIdx.x;
    if (idx >= M * N) return;
    const int n = idx % N;
    float s = 0.f;
    for (int k = 0; k < nsplit; k++) s += P[(size_t)k * M * N + idx];
    H[idx] = gelu_exact(s + bias[n]);
}

__global__ __launch_bounds__(256) void reduce_sum_parts(
    const float* __restrict__ P, float* __restrict__ Y, int MN, int nsplit)
{
    const int idx = blockIdx.x * 256 + threadIdx.x;
    if (idx >= MN) return;
    float s = 0.f;
    for (int k = 0; k < nsplit; k++) s += P[(size_t)k * MN + idx];
    Y[idx] = s;
}

// Per-row exact K-th-largest via 4-pass radix select on float bits (all >=0).
__global__ __launch_bounds__(256) void topk_thresh(
    const float* __restrict__ U, int N, int Kq, float* __restrict__ tout)
{
    __shared__ unsigned int hist[256];
    __shared__ unsigned int s_pref;
    __shared__ int s_rem;
    const int row = blockIdx.x, t = threadIdx.x;
    const float* u = U + (size_t)row * N;
    unsigned int pref = 0, pmask = 0;
    int remain = Kq;
    for (int pass = 0; pass < 4; pass++) {
        const int shift = 24 - 8 * pass;
        hist[t] = 0;
        __syncthreads();
        for (int j = t; j < N; j += 256) {
            const unsigned int v = __float_as_uint(u[j]);
            if ((v & pmask) == pref) atomicAdd(&hist[(v >> shift) & 0xFFu], 1u);
        }
        __syncthreads();
        if (t == 0) {
            unsigned int cum = 0; int b = 255;
            for (; b >= 0; b--) {
                const unsigned int h = hist[b];
                if (cum + h >= (unsigned int)remain) break;
                cum += h;
            }
            if (b < 0) b = 0;
            s_pref = pref | ((unsigned int)b << shift);
            s_rem  = remain - (int)cum;
        }
        __syncthreads();
        pref = s_pref; remain = s_rem;
        pmask |= (0xFFu << shift);
        __syncthreads();
    }
    if (t == 0) tout[row] = __uint_as_float(pref);
}

// U1 := clip(sr + dsp,0) - clip(dsm,0); row-sums of dsp/dsm for loss_sparse.
__global__ __launch_bounds__(256) void build_sq(
    float* __restrict__ U1, const float* __restrict__ U2,
    const float* __restrict__ sr,
    const float* __restrict__ tp, const float* __restrict__ tm,
    float* __restrict__ sparse_p, float* __restrict__ sparse_m)
{
    __shared__ float red[256];
    const int row = blockIdx.x, t = threadIdx.x;
    const float thp = tp[row], thm = tm[row];
    float* u1 = U1 + (size_t)row * VSZ;
    const float* u2 = U2 + (size_t)row * VSZ;
    const float* s  = sr + (size_t)row * VSZ;
    float sp = 0.f, sm = 0.f;
    for (int j = t; j < VSZ; j += 256) {
        const float up = u1[j], um = u2[j];
        const float dp = (up >= thp) ? up : 0.f;
        const float dm = (um >= thm) ? um : 0.f;
        sp += dp; sm += dm;
        u1[j] = fmaxf(s[j] + dp, 0.f) - fmaxf(dm, 0.f);
    }
    red[t] = sp; __syncthreads();
    for (int o = 128; o > 0; o >>= 1) { if (t < o) red[t] += red[t + o]; __syncthreads(); }
    if (t == 0) sparse_p[row] = red[0];
    __syncthreads();
    red[t] = sm; __syncthreads();
    for (int o = 128; o > 0; o >>= 1) { if (t < o) red[t] += red[t + o]; __syncthreads(); }
    if (t == 0) sparse_m[row] = red[0];
}

__global__ __launch_bounds__(256) void rownorm(
    const float* __restrict__ X, float* __restrict__ Y, int dbl)
{
    __shared__ float red[256];
    const int row = blockIdx.x, t = threadIdx.x;
    const float* x = X + (size_t)row * DIM;
    float* y = Y + (size_t)row * DIM;
    float v0 = x[t], v1 = x[t + 256], v2 = x[t + 512];
    red[t] = v0 * v0 + v1 * v1 + v2 * v2; __syncthreads();
    for (int o = 128; o > 0; o >>= 1) { if (t < o) red[t] += red[t + o]; __syncthreads(); }
    const float nrm = sqrtf(red[0]) + EPSN;
    v0 /= nrm; v1 /= nrm; v2 /= nrm;
    if (dbl) {
        __syncthreads();
        red[t] = v0 * v0 + v1 * v1 + v2 * v2; __syncthreads();
        for (int o = 128; o > 0; o >>= 1) { if (t < o) red[t] += red[t + o]; __syncthreads(); }
        const float n2 = sqrtf(red[0]) + EPSN;
        v0 /= n2; v1 /= n2; v2 /= n2;
    }
    y[t] = v0; y[t + 256] = v1; y[t + 512] = v2;
}

__global__ __launch_bounds__(256) void pos_dot(
    const float* __restrict__ zq, const float* __restrict__ zp,
    float* __restrict__ posL)
{
    __shared__ float red[256];
    const int row = blockIdx.x, t = threadIdx.x;
    const float* a = zq + (size_t)row * DIM;
    const float* b = zp + (size_t)row * DIM;
    red[t] = a[t] * b[t] + a[t + 256] * b[t + 256] + a[t + 512] * b[t + 512];
    __syncthreads();
    for (int o = 128; o > 0; o >>= 1) { if (t < o) red[t] += red[t + o]; __syncthreads(); }
    if (t == 0) posL[row] = red[0] / TEMPC;
}

// NegL holds raw dot products; scale by 1/TEMP here.
__global__ __launch_bounds__(256) void lse_loss(
    const float* __restrict__ negL, const float* __restrict__ posL,
    float* __restrict__ rowL)
{
    __shared__ float red[256];
    const int row = blockIdx.x, t = threadIdx.x;
    const float* nl = negL + (size_t)row * MNEG;
    const float p = posL[row];
    float lmax = (t == 0) ? p : -INFINITY;
    for (int j = t; j < MNEG; j += 256) lmax = fmaxf(lmax, nl[j] * INVT);
    red[t] = lmax; __syncthreads();
    for (int o = 128; o > 0; o >>= 1) { if (t < o) red[t] = fmaxf(red[t], red[t + o]); __syncthreads(); }
    const float mx = red[0];
    __syncthreads();
    float lsum = (t == 0) ? expf(p - mx) : 0.f;
    for (int j = t; j < MNEG; j += 256) lsum += expf(nl[j] * INVT - mx);
    red[t] = lsum; __syncthreads();
    for (int o = 128; o > 0; o >>= 1) { if (t < o) red[t] += red[t + o]; __syncthreads(); }
    if (t == 0) rowL[row] = mx + logf(red[0]) - p;
}

__global__ __launch_bounds__(256) void rec_row(
    const float* __restrict__ zhat, const float* __restrict__ zrn,
    float* __restrict__ part)
{
    __shared__ float red[256];
    const int row = blockIdx.x, t = threadIdx.x;
    const float* a = zhat + (size_t)row * DIM;
    const float* b = zrn + (size_t)row * DIM;
    const float d0 = a[t] - b[t], d1 = a[t + 256] - b[t + 256], d2 = a[t + 512] - b[t + 512];
    red[t] = d0 * d0 + d1 * d1 + d2 * d2;
    __syncthreads();
    for (int o = 128; o > 0; o >>= 1) { if (t < o) red[t] += red[t + o]; __syncthreads(); }
    if (t == 0) part[row] = red[0];
}

__global__ __launch_bounds__(256) void final_combine(
    const float* __restrict__ rowL, const float* __restrict__ recP,
    const float* __restrict__ spP, const float* __restrict__ spM,
    float* __restrict__ out)
{
    __shared__ float red[256];
    const int t = threadIdx.x;
    red[t] = rowL[t]; __syncthreads();
    for (int o = 128; o > 0; o >>= 1) { if (t < o) red[t] += red[t + o]; __syncthreads(); }
    const float retr = red[0] / 256.0f;
    __syncthreads();
    red[t] = recP[t]; __syncthreads();
    for (int o = 128; o > 0; o >>= 1) { if (t < o) red[t] += red[t + o]; __syncthreads(); }
    const float rec = red[0] / (float)(BATCH * DIM);
    __syncthreads();
    red[t] = spP[t] + spM[t]; __syncthreads();
    for (int o = 128; o > 0; o >>= 1) { if (t < o) red[t] += red[t + o]; __syncthreads(); }
    const float sparse = red[0] / 256.0f;
    if (t == 0) out[0] = retr + 1.0f * rec + 1e-4f * sparse;
}

extern "C" void kernel_launch(void* const* d_in, const int* in_sizes, int n_in,
                              void* d_out, int out_size, void* d_ws, size_t ws_size,
                              hipStream_t stream)
{
    const float* ht   = (const float*)d_in[0];
    const float* sr   = (const float*)d_in[1];
    const float* zpos = (const float*)d_in[2];
    const float* zneg = (const float*)d_in[3];
    const float* zr   = (const float*)d_in[4];
    const float* W1p  = (const float*)d_in[5];
    const float* b1p  = (const float*)d_in[6];
    const float* W2p  = (const float*)d_in[7];
    const float* b2p  = (const float*)d_in[8];
    const float* W1m  = (const float*)d_in[9];
    const float* b1m  = (const float*)d_in[10];
    const float* W2m  = (const float*)d_in[11];
    const float* b2m  = (const float*)d_in[12];
    const float* Wdec = (const float*)d_in[13];
    float* out = (float*)d_out;

    // workspace layout (bytes) — unchanged from round 3
    char* ws = (char*)d_ws;
    float* U1   = (float*)(ws + 0);            // 31,254,528
    float* U2   = (float*)(ws + 31254528);     // 31,254,528
    float* P    = (float*)(ws + 62509056);     // 33,554,432 partial arena (serial reuse)
    float* P1g  = (float*)(ws + 62509056 + 16777216);  // gemm1 branch-m partials
    float* P1d  = (float*)(ws + 62509056 + 12582912);  // decode branch-sr partials
    float* Hp   = (float*)(ws + 96063488);     //      524,288
    float* Hm   = (float*)(ws + 96587776);     //      524,288
    float* Y1   = (float*)(ws + 97112064);     //      786,432
    float* Y2   = (float*)(ws + 97898496);     //      786,432
    float* Zn   = (float*)(ws + 98684928);     //   12,582,912
    float* Zp   = (float*)(ws + 111267840);    //      786,432
    float* Zrn  = (float*)(ws + 112054272);    //      786,432
    float* NegL = (float*)(ws + 112840704);    //    4,194,304
    float* tP   = (float*)(ws + 117035008);    // small vectors (256 floats each)
    float* tM   = tP + 256;
    float* spP  = tP + 512;
    float* spM  = tP + 768;
    float* posL = tP + 1024;
    float* rowL = tP + 1280;
    float* recP = tP + 1536;
    (void)in_sizes; (void)n_in; (void)out_size; (void)ws_size;

    const dim3 blk(256);

    // ---- GEMM1 dual (ht@W1p | ht@W1m), split-K 32 each, grid 512 blocks
    gemm32t<0,0,0><<<dim3(2,4,64), blk, 0, stream>>>(
        ht, ht, VSZ, W1p, W1m, BOT, P, P1g, nullptr, nullptr,
        BOT, VSZ, 32, BATCH*BOT);
    reduce_bias_gelu<<<dim3(512), blk, 0, stream>>>(P,   b1p, Hp, BATCH, BOT, 32);
    reduce_bias_gelu<<<dim3(512), blk, 0, stream>>>(P1g, b1m, Hm, BATCH, BOT, 32);

    // ---- GEMM2 dual (Hp@W2p | Hm@W2m), fused softplus+bias, grid 956 blocks
    gemm32t<0,1,1><<<dim3(2,239,2), blk, 0, stream>>>(
        Hp, Hm, BOT, W2p, W2m, VSZ, U1, U2, b2p, b2m,
        VSZ, BOT, 1, 0);

    // ---- exact top-K thresholds, then sq build + sparse row sums
    topk_thresh<<<dim3(256), blk, 0, stream>>>(U1, VSZ, KDELT, tP);
    topk_thresh<<<dim3(256), blk, 0, stream>>>(U2, VSZ, KDELT, tM);
    build_sq<<<dim3(256), blk, 0, stream>>>(U1, U2, sr, tP, tM, spP, spM);

    // ---- decode dual (sq@Wdec | sr@Wdec), split-K 16, grid 384 blocks
    gemm32t<0,0,0><<<dim3(2,6,32), blk, 0, stream>>>(
        U1, sr, VSZ, Wdec, Wdec, DIM, P, P1d, nullptr, nullptr,
        DIM, VSZ, 16, BATCH*DIM);
    reduce_sum_parts<<<dim3(768), blk, 0, stream>>>(P,   Y1, BATCH*DIM, 16);
    reduce_sum_parts<<<dim3(768), blk, 0, stream>>>(P1d, Y2, BATCH*DIM, 16);

    // ---- normalizations
    rownorm<<<dim3(256),  blk, 0, stream>>>(Y1, Y1, 1);   // zq (double norm)
    rownorm<<<dim3(256),  blk, 0, stream>>>(Y2, Y2, 0);   // zhat_r
    rownorm<<<dim3(4096), blk, 0, stream>>>(zneg, Zn, 0);
    rownorm<<<dim3(256),  blk, 0, stream>>>(zpos, Zp, 0);
    rownorm<<<dim3(256),  blk, 0, stream>>>(zr,   Zrn, 0);

    // ---- retrieval loss
    pos_dot<<<dim3(256), blk, 0, stream>>>(Y1, Zp, posL);
    gemm32t<1,0,0><<<dim3(2,32,4), blk, 0, stream>>>(
        Y1, Y1, DIM, Zn, Zn, DIM, P, P, nullptr, nullptr,
        MNEG, DIM, 4, BATCH*MNEG);
    reduce_sum_parts<<<dim3(4096), blk, 0, stream>>>(P, NegL, BATCH*MNEG, 4);
    lse_loss<<<dim3(256), blk, 0, stream>>>(NegL, posL, rowL);

    // ---- reconstruction loss
    rec_row<<<dim3(256), blk, 0, stream>>>(Y2, Zrn, recP);

    // ---- combine
    final_combine<<<dim3(1), blk, 0, stream>>>(rowL, recP, spP, spM, out);
}

// Round 5
// 436.204 us; speedup vs baseline: 5.2980x; 1.6728x over previous
//
#include <hip/hip_runtime.h>
#include <math.h>

#define VSZ   30522
#define DIM   768
#define KDELT 768
#define BOT   512
#define BATCH 256
#define MNEG  4096
#define EPSN  1e-6f
#define TEMPC 0.05f
#define INVT  20.0f
#define TKT   1024

typedef _Float16 f16;
typedef _Float16 f16x8 __attribute__((ext_vector_type(8)));
typedef _Float16 f16x2 __attribute__((ext_vector_type(2)));
typedef float    f32x4 __attribute__((ext_vector_type(4)));

static __device__ __forceinline__ float gelu_exact(float x){
    return 0.5f * x * (1.0f + erff(x * 0.70710678118654752440f));
}
static __device__ __forceinline__ float softplus_f(float x){
    return fmaxf(x, 0.0f) + log1pf(expf(-fabsf(x)));
}

// ---------------------------------------------------------------------------
// fp32-in / fp16-MFMA GEMM, register-batched staging + next-tile prefetch.
// (unchanged from round 4 — see comments there)
// ---------------------------------------------------------------------------
template<int BSRC, int NG, int EPI>
__global__ __launch_bounds__(256, 2) void gemm32t(
    const float* __restrict__ A0, const float* __restrict__ A1, int lda,
    const float* __restrict__ B0, const float* __restrict__ B1, int ldb,
    float* __restrict__ C0, float* __restrict__ C1,
    const float* __restrict__ bias0, const float* __restrict__ bias1,
    int N, int K, int nsplit, int MN)
{
    __shared__ f16 Al[128][40];
    __shared__ f16 Bl[128][40];
    const int t  = threadIdx.x;
    const int m0 = blockIdx.x * 128;
    const int n0 = blockIdx.y * 128;
    const int br = blockIdx.z / nsplit;
    const int s  = blockIdx.z % nsplit;
    const float* __restrict__ A = br ? A1 : A0;
    const float* __restrict__ B = br ? B1 : B0;
    float* __restrict__ C       = br ? C1 : C0;
    const float* __restrict__ bias = br ? bias1 : bias0;

    const int kchunk = ((K + nsplit * 32 - 1) / (nsplit * 32)) * 32;
    const int kb = s * kchunk;
    const int ke = min(K, kb + kchunk);

    const int sr_ = t >> 4;          // staging row-in-pass 0..15
    const int sc  = (t & 15) * 2;    // staging col pair 0..30
    const int bn  = t & 127;         // B transpose staging n
    const int bk  = t >> 7;          // 0..1

    const int lane = t & 63, w = t >> 6;
    const int wr = (w >> 1) * 64, wc = (w & 1) * 64;
    const int fr = lane & 15, kg = (lane >> 4) * 8;

    f32x4 acc[4][4] = {};

    float2 ra[8];
    float  rb[16];
    float2 rb2[8];

    auto loadA = [&](int k0, int krem) {
        #pragma unroll
        for (int p = 0; p < 8; p++) {
            const int row = p * 16 + sr_;
            float2 u = {0.f, 0.f};
            if (sc < krem) u = *(const float2*)(A + (size_t)(m0 + row) * lda + k0 + sc);
            ra[p] = u;
        }
    };
    auto loadB = [&](int k0, int krem) {
        if (BSRC == 0) {
            const bool nok = (!NG) || (n0 + bn < N);
            #pragma unroll
            for (int p = 0; p < 16; p++) {
                const int kk = p * 2 + bk;
                float x = 0.f;
                if (kk < krem && nok) x = B[(size_t)(k0 + kk) * ldb + n0 + bn];
                rb[p] = x;
            }
        } else {
            #pragma unroll
            for (int p = 0; p < 8; p++) {
                const int row = p * 16 + sr_;
                float2 u = {0.f, 0.f};
                if (sc < krem) u = *(const float2*)(B + (size_t)(n0 + row) * ldb + k0 + sc);
                rb2[p] = u;
            }
        }
    };
    auto storeA = [&]() {
        #pragma unroll
        for (int p = 0; p < 8; p++) {
            f16x2 v; v[0] = (f16)ra[p].x; v[1] = (f16)ra[p].y;
            *(f16x2*)&Al[p * 16 + sr_][sc] = v;
        }
    };
    auto storeB = [&]() {
        if (BSRC == 0) {
            #pragma unroll
            for (int p = 0; p < 16; p++)
                Bl[bn][p * 2 + bk] = (f16)rb[p];
        } else {
            #pragma unroll
            for (int p = 0; p < 8; p++) {
                f16x2 v; v[0] = (f16)rb2[p].x; v[1] = (f16)rb2[p].y;
                *(f16x2*)&Bl[p * 16 + sr_][sc] = v;
            }
        }
    };

    int k0 = kb;
    {
        const int kr = min(32, ke - k0);
        loadA(k0, kr); loadB(k0, kr);
    }
    while (k0 < ke) {
        storeA(); storeB();
        __syncthreads();
        const int k1 = k0 + 32;
        if (k1 < ke) {                       // prefetch next tile into regs
            const int kr = min(32, ke - k1);
            loadA(k1, kr); loadB(k1, kr);
        }
        f16x8 af[4], bf[4];
        #pragma unroll
        for (int m = 0; m < 4; m++) af[m] = *(const f16x8*)&Al[wr + m * 16 + fr][kg];
        #pragma unroll
        for (int n = 0; n < 4; n++) bf[n] = *(const f16x8*)&Bl[wc + n * 16 + fr][kg];
        #pragma unroll
        for (int m = 0; m < 4; m++)
            #pragma unroll
            for (int n = 0; n < 4; n++)
                acc[m][n] = __builtin_amdgcn_mfma_f32_16x16x32_f16(af[m], bf[n], acc[m][n], 0, 0, 0);
        __syncthreads();
        k0 = k1;
    }

    float* Cp = (EPI == 0) ? (C + (size_t)s * MN) : C;
    #pragma unroll
    for (int m = 0; m < 4; m++) {
        #pragma unroll
        for (int n = 0; n < 4; n++) {
            #pragma unroll
            for (int j = 0; j < 4; j++) {
                const int row = m0 + wr + m * 16 + (lane >> 4) * 4 + j;
                const int col = n0 + wc + n * 16 + fr;
                if (NG && col >= N) continue;
                if (EPI == 0) Cp[(size_t)row * N + col] = acc[m][n][j];
                else          Cp[(size_t)row * N + col] = softplus_f(acc[m][n][j] + bias[col]);
            }
        }
    }
}

// dual-branch split-K reduce + bias + exact GELU
__global__ __launch_bounds__(256) void reduce_bias_gelu2(
    const float* __restrict__ P0, const float* __restrict__ P1,
    const float* __restrict__ bias0, const float* __restrict__ bias1,
    float* __restrict__ H0, float* __restrict__ H1,
    int MN, int N, int nsplit)
{
    const int idx = blockIdx.x * 256 + threadIdx.x;
    if (idx >= MN) return;
    const int n = idx % N;
    const float* P = blockIdx.y ? P1 : P0;
    const float* bias = blockIdx.y ? bias1 : bias0;
    float* H = blockIdx.y ? H1 : H0;
    float s = 0.f;
    for (int k = 0; k < nsplit; k++) s += P[(size_t)k * MN + idx];
    H[idx] = gelu_exact(s + bias[n]);
}

__global__ __launch_bounds__(256) void reduce_sum_parts(
    const float* __restrict__ P, float* __restrict__ Y, int MN, int nsplit)
{
    const int idx = blockIdx.x * 256 + threadIdx.x;
    if (idx >= MN) return;
    float s = 0.f;
    for (int k = 0; k < nsplit; k++) s += P[(size_t)k * MN + idx];
    Y[idx] = s;
}

// ---------------------------------------------------------------------------
// Exact per-row K-th-largest via 12/12/7-bit radix select on float bits
// (all values >= 0 so uint order == float order). 4096 LDS bins spread the
// softplus value concentration (old 8-bit-exponent pass had ~all elements in
// a few bins -> same-address atomic serialization, 153 us). Both branches in
// one launch: grid (2, 256). Boundary bin found by block suffix-scan.
// ---------------------------------------------------------------------------
__global__ __launch_bounds__(TKT) void topk_thresh2(
    const float* __restrict__ U1, const float* __restrict__ U2,
    float* __restrict__ tP, float* __restrict__ tM)
{
    __shared__ unsigned int hist[4096];
    __shared__ unsigned int scan[TKT];
    __shared__ unsigned int s_pref;
    __shared__ int s_rem;
    const int row = blockIdx.y, t = threadIdx.x;
    const float* u = (blockIdx.x ? U2 : U1) + (size_t)row * VSZ;
    float* tout = blockIdx.x ? tM : tP;

    unsigned int pref = 0;
    int remain = KDELT;

    #pragma unroll
    for (int p = 0; p < 3; p++) {
        for (int i = t; i < 4096; i += TKT) hist[i] = 0;
        __syncthreads();
        for (int j = t; j < VSZ / 2; j += TKT) {
            const float2 x = *(const float2*)(u + 2 * j);
            const unsigned int v0 = __float_as_uint(x.x);
            const unsigned int v1 = __float_as_uint(x.y);
            if (p == 0) {
                atomicAdd(&hist[v0 >> 19], 1u);
                atomicAdd(&hist[v1 >> 19], 1u);
            } else if (p == 1) {
                if ((v0 >> 19) == pref) atomicAdd(&hist[(v0 >> 7) & 0xFFFu], 1u);
                if ((v1 >> 19) == pref) atomicAdd(&hist[(v1 >> 7) & 0xFFFu], 1u);
            } else {
                if ((v0 >> 7) == pref) atomicAdd(&hist[v0 & 0x7Fu], 1u);
                if ((v1 >> 7) == pref) atomicAdd(&hist[v1 & 0x7Fu], 1u);
            }
        }
        __syncthreads();
        // suffix scan: thread t owns bins [4t, 4t+4)
        unsigned int loc = hist[4 * t] + hist[4 * t + 1] + hist[4 * t + 2] + hist[4 * t + 3];
        scan[t] = loc;
        __syncthreads();
        for (int o = 1; o < TKT; o <<= 1) {
            const unsigned int v = (t + o < TKT) ? scan[t + o] : 0u;
            __syncthreads();
            scan[t] += v;
            __syncthreads();
        }
        const unsigned int above = (t + 1 < TKT) ? scan[t + 1] : 0u;
        if (scan[t] >= (unsigned int)remain && above < (unsigned int)remain) {
            unsigned int cum = above;
            #pragma unroll
            for (int bi = 3; bi >= 0; bi--) {
                const int b = 4 * t + bi;
                cum += hist[b];
                if (cum >= (unsigned int)remain) {
                    s_pref = (unsigned int)b;
                    s_rem  = remain - (int)(cum - hist[b]);
                    break;
                }
            }
        }
        __syncthreads();
        if (p == 0)      pref = s_pref;
        else if (p == 1) pref = (pref << 12) | s_pref;
        else             pref = (pref << 7)  | s_pref;
        remain = s_rem;
        __syncthreads();
    }
    if (t == 0) tout[row] = __uint_as_float(pref);
}

// U1 := clip(sr + dsp,0) - clip(dsm,0); row-sums of dsp/dsm for loss_sparse.
__global__ __launch_bounds__(256) void build_sq(
    float* __restrict__ U1, const float* __restrict__ U2,
    const float* __restrict__ sr,
    const float* __restrict__ tp, const float* __restrict__ tm,
    float* __restrict__ sparse_p, float* __restrict__ sparse_m)
{
    __shared__ float red[256];
    const int row = blockIdx.x, t = threadIdx.x;
    const float thp = tp[row], thm = tm[row];
    float* u1 = U1 + (size_t)row * VSZ;
    const float* u2 = U2 + (size_t)row * VSZ;
    const float* s  = sr + (size_t)row * VSZ;
    float sp = 0.f, sm = 0.f;
    for (int j = t; j < VSZ / 2; j += 256) {
        const float2 up = *(const float2*)(u1 + 2 * j);
        const float2 um = *(const float2*)(u2 + 2 * j);
        const float2 ss = *(const float2*)(s  + 2 * j);
        const float dp0 = (up.x >= thp) ? up.x : 0.f;
        const float dp1 = (up.y >= thp) ? up.y : 0.f;
        const float dm0 = (um.x >= thm) ? um.x : 0.f;
        const float dm1 = (um.y >= thm) ? um.y : 0.f;
        sp += dp0 + dp1; sm += dm0 + dm1;
        float2 o;
        o.x = fmaxf(ss.x + dp0, 0.f) - fmaxf(dm0, 0.f);
        o.y = fmaxf(ss.y + dp1, 0.f) - fmaxf(dm1, 0.f);
        *(float2*)(u1 + 2 * j) = o;
    }
    red[t] = sp; __syncthreads();
    for (int o = 128; o > 0; o >>= 1) { if (t < o) red[t] += red[t + o]; __syncthreads(); }
    if (t == 0) sparse_p[row] = red[0];
    __syncthreads();
    red[t] = sm; __syncthreads();
    for (int o = 128; o > 0; o >>= 1) { if (t < o) red[t] += red[t + o]; __syncthreads(); }
    if (t == 0) sparse_m[row] = red[0];
}

__global__ __launch_bounds__(256) void rownorm(
    const float* __restrict__ X, float* __restrict__ Y, int dbl)
{
    __shared__ float red[256];
    const int row = blockIdx.x, t = threadIdx.x;
    const float* x = X + (size_t)row * DIM;
    float* y = Y + (size_t)row * DIM;
    float v0 = x[t], v1 = x[t + 256], v2 = x[t + 512];
    red[t] = v0 * v0 + v1 * v1 + v2 * v2; __syncthreads();
    for (int o = 128; o > 0; o >>= 1) { if (t < o) red[t] += red[t + o]; __syncthreads(); }
    const float nrm = sqrtf(red[0]) + EPSN;
    v0 /= nrm; v1 /= nrm; v2 /= nrm;
    if (dbl) {
        __syncthreads();
        red[t] = v0 * v0 + v1 * v1 + v2 * v2; __syncthreads();
        for (int o = 128; o > 0; o >>= 1) { if (t < o) red[t] += red[t + o]; __syncthreads(); }
        const float n2 = sqrtf(red[0]) + EPSN;
        v0 /= n2; v1 /= n2; v2 /= n2;
    }
    y[t] = v0; y[t + 256] = v1; y[t + 512] = v2;
}

__global__ __launch_bounds__(256) void pos_dot(
    const float* __restrict__ zq, const float* __restrict__ zp,
    float* __restrict__ posL)
{
    __shared__ float red[256];
    const int row = blockIdx.x, t = threadIdx.x;
    const float* a = zq + (size_t)row * DIM;
    const float* b = zp + (size_t)row * DIM;
    red[t] = a[t] * b[t] + a[t + 256] * b[t + 256] + a[t + 512] * b[t + 512];
    __syncthreads();
    for (int o = 128; o > 0; o >>= 1) { if (t < o) red[t] += red[t + o]; __syncthreads(); }
    if (t == 0) posL[row] = red[0] / TEMPC;
}

// NegL holds raw dot products; scale by 1/TEMP here.
__global__ __launch_bounds__(256) void lse_loss(
    const float* __restrict__ negL, const float* __restrict__ posL,
    float* __restrict__ rowL)
{
    __shared__ float red[256];
    const int row = blockIdx.x, t = threadIdx.x;
    const float* nl = negL + (size_t)row * MNEG;
    const float p = posL[row];
    float lmax = (t == 0) ? p : -INFINITY;
    for (int j = t; j < MNEG; j += 256) lmax = fmaxf(lmax, nl[j] * INVT);
    red[t] = lmax; __syncthreads();
    for (int o = 128; o > 0; o >>= 1) { if (t < o) red[t] = fmaxf(red[t], red[t + o]); __syncthreads(); }
    const float mx = red[0];
    __syncthreads();
    float lsum = (t == 0) ? expf(p - mx) : 0.f;
    for (int j = t; j < MNEG; j += 256) lsum += expf(nl[j] * INVT - mx);
    red[t] = lsum; __syncthreads();
    for (int o = 128; o > 0; o >>= 1) { if (t < o) red[t] += red[t + o]; __syncthreads(); }
    if (t == 0) rowL[row] = mx + logf(red[0]) - p;
}

__global__ __launch_bounds__(256) void rec_row(
    const float* __restrict__ zhat, const float* __restrict__ zrn,
    float* __restrict__ part)
{
    __shared__ float red[256];
    const int row = blockIdx.x, t = threadIdx.x;
    const float* a = zhat + (size_t)row * DIM;
    const float* b = zrn + (size_t)row * DIM;
    const float d0 = a[t] - b[t], d1 = a[t + 256] - b[t + 256], d2 = a[t + 512] - b[t + 512];
    red[t] = d0 * d0 + d1 * d1 + d2 * d2;
    __syncthreads();
    for (int o = 128; o > 0; o >>= 1) { if (t < o) red[t] += red[t + o]; __syncthreads(); }
    if (t == 0) part[row] = red[0];
}

__global__ __launch_bounds__(256) void final_combine(
    const float* __restrict__ rowL, const float* __restrict__ recP,
    const float* __restrict__ spP, const float* __restrict__ spM,
    float* __restrict__ out)
{
    __shared__ float red[256];
    const int t = threadIdx.x;
    red[t] = rowL[t]; __syncthreads();
    for (int o = 128; o > 0; o >>= 1) { if (t < o) red[t] += red[t + o]; __syncthreads(); }
    const float retr = red[0] / 256.0f;
    __syncthreads();
    red[t] = recP[t]; __syncthreads();
    for (int o = 128; o > 0; o >>= 1) { if (t < o) red[t] += red[t + o]; __syncthreads(); }
    const float rec = red[0] / (float)(BATCH * DIM);
    __syncthreads();
    red[t] = spP[t] + spM[t]; __syncthreads();
    for (int o = 128; o > 0; o >>= 1) { if (t < o) red[t] += red[t + o]; __syncthreads(); }
    const float sparse = red[0] / 256.0f;
    if (t == 0) out[0] = retr + 1.0f * rec + 1e-4f * sparse;
}

extern "C" void kernel_launch(void* const* d_in, const int* in_sizes, int n_in,
                              void* d_out, int out_size, void* d_ws, size_t ws_size,
                              hipStream_t stream)
{
    const float* ht   = (const float*)d_in[0];
    const float* sr   = (const float*)d_in[1];
    const float* zpos = (const float*)d_in[2];
    const float* zneg = (const float*)d_in[3];
    const float* zr   = (const float*)d_in[4];
    const float* W1p  = (const float*)d_in[5];
    const float* b1p  = (const float*)d_in[6];
    const float* W2p  = (const float*)d_in[7];
    const float* b2p  = (const float*)d_in[8];
    const float* W1m  = (const float*)d_in[9];
    const float* b1m  = (const float*)d_in[10];
    const float* W2m  = (const float*)d_in[11];
    const float* b2m  = (const float*)d_in[12];
    const float* Wdec = (const float*)d_in[13];
    float* out = (float*)d_out;

    // workspace layout (bytes) — unchanged
    char* ws = (char*)d_ws;
    float* U1   = (float*)(ws + 0);            // 31,254,528
    float* U2   = (float*)(ws + 31254528);     // 31,254,528
    float* P    = (float*)(ws + 62509056);     // 33,554,432 partial arena (serial reuse)
    float* P1g  = (float*)(ws + 62509056 + 16777216);  // gemm1 branch-m partials
    float* P1d  = (float*)(ws + 62509056 + 12582912);  // decode branch-sr partials
    float* Hp   = (float*)(ws + 96063488);     //      524,288
    float* Hm   = (float*)(ws + 96587776);     //      524,288
    float* Y1   = (float*)(ws + 97112064);     //      786,432
    float* Y2   = (float*)(ws + 97898496);     //      786,432
    float* Zn   = (float*)(ws + 98684928);     //   12,582,912
    float* Zp   = (float*)(ws + 111267840);    //      786,432
    float* Zrn  = (float*)(ws + 112054272);    //      786,432
    float* NegL = (float*)(ws + 112840704);    //    4,194,304
    float* tP   = (float*)(ws + 117035008);    // small vectors (256 floats each)
    float* tM   = tP + 256;
    float* spP  = tP + 512;
    float* spM  = tP + 768;
    float* posL = tP + 1024;
    float* rowL = tP + 1280;
    float* recP = tP + 1536;
    (void)in_sizes; (void)n_in; (void)out_size; (void)ws_size;

    const dim3 blk(256);

    // ---- GEMM1 dual (ht@W1p | ht@W1m), split-K 32 each, grid 512 blocks
    gemm32t<0,0,0><<<dim3(2,4,64), blk, 0, stream>>>(
        ht, ht, VSZ, W1p, W1m, BOT, P, P1g, nullptr, nullptr,
        BOT, VSZ, 32, BATCH*BOT);
    reduce_bias_gelu2<<<dim3(512,2), blk, 0, stream>>>(
        P, P1g, b1p, b1m, Hp, Hm, BATCH*BOT, BOT, 32);

    // ---- GEMM2 dual (Hp@W2p | Hm@W2m), fused softplus+bias, grid 956 blocks
    gemm32t<0,1,1><<<dim3(2,239,2), blk, 0, stream>>>(
        Hp, Hm, BOT, W2p, W2m, VSZ, U1, U2, b2p, b2m,
        VSZ, BOT, 1, 0);

    // ---- exact top-K thresholds (both branches, one launch)
    topk_thresh2<<<dim3(2,256), dim3(TKT), 0, stream>>>(U1, U2, tP, tM);
    build_sq<<<dim3(256), blk, 0, stream>>>(U1, U2, sr, tP, tM, spP, spM);

    // ---- decode dual (sq@Wdec | sr@Wdec), split-K 16, grid 384 blocks
    gemm32t<0,0,0><<<dim3(2,6,32), blk, 0, stream>>>(
        U1, sr, VSZ, Wdec, Wdec, DIM, P, P1d, nullptr, nullptr,
        DIM, VSZ, 16, BATCH*DIM);
    reduce_sum_parts<<<dim3(768), blk, 0, stream>>>(P,   Y1, BATCH*DIM, 16);
    reduce_sum_parts<<<dim3(768), blk, 0, stream>>>(P1d, Y2, BATCH*DIM, 16);

    // ---- normalizations
    rownorm<<<dim3(256),  blk, 0, stream>>>(Y1, Y1, 1);   // zq (double norm)
    rownorm<<<dim3(256),  blk, 0, stream>>>(Y2, Y2, 0);   // zhat_r
    rownorm<<<dim3(4096), blk, 0, stream>>>(zneg, Zn, 0);
    rownorm<<<dim3(256),  blk, 0, stream>>>(zpos, Zp, 0);
    rownorm<<<dim3(256),  blk, 0, stream>>>(zr,   Zrn, 0);

    // ---- retrieval loss
    pos_dot<<<dim3(256), blk, 0, stream>>>(Y1, Zp, posL);
    gemm32t<1,0,0><<<dim3(2,32,4), blk, 0, stream>>>(
        Y1, Y1, DIM, Zn, Zn, DIM, P, P, nullptr, nullptr,
        MNEG, DIM, 4, BATCH*MNEG);
    reduce_sum_parts<<<dim3(4096), blk, 0, stream>>>(P, NegL, BATCH*MNEG, 4);
    lse_loss<<<dim3(256), blk, 0, stream>>>(NegL, posL, rowL);

    // ---- reconstruction loss
    rec_row<<<dim3(256), blk, 0, stream>>>(Y2, Zrn, recP);

    // ---- combine
    final_combine<<<dim3(1), blk, 0, stream>>>(rowL, recP, spP, spM, out);
}

// Round 7
// 427.533 us; speedup vs baseline: 5.4055x; 1.0203x over previous
//
#include <hip/hip_runtime.h>
#include <math.h>

#define VSZ   30522
#define DIM   768
#define KDELT 768
#define BOT   512
#define BATCH 256
#define MNEG  4096
#define EPSN  1e-6f
#define TEMPC 0.05f
#define INVT  20.0f
#define TKT   1024

typedef _Float16 f16;
typedef _Float16 f16x8 __attribute__((ext_vector_type(8)));
typedef _Float16 f16x2 __attribute__((ext_vector_type(2)));
typedef float    f32x4 __attribute__((ext_vector_type(4)));

static __device__ __forceinline__ float gelu_exact(float x){
    return 0.5f * x * (1.0f + erff(x * 0.70710678118654752440f));
}
static __device__ __forceinline__ float softplus_f(float x){
    return fmaxf(x, 0.0f) + log1pf(expf(-fabsf(x)));
}
// v_cvt_pkrtz_f16_f32 wrapper: builtin returns __fp16 vector; bit-cast to our
// _Float16 vector type (same bits, different clang type).
static __device__ __forceinline__ f16x2 pkh(float a, float b){
    return __builtin_bit_cast(f16x2, __builtin_amdgcn_cvt_pkrtz(a, b));
}

// ---------------------------------------------------------------------------
// fp32-in / fp16-MFMA GEMM, register-batched staging + next-tile prefetch.
// R5: staging VALU diet — B-transpose path packs 16 contiguous k per thread
// with v_cvt_pkrtz and writes two ds_write_b128 (was 16 ds_write_b16, the
// 8.8M bank-conflict source); A path packs with cvt_pkrtz (8 instead of 16
// converts). VALUBusy was 56% with MfmaUtil 5% — staging ops dominated.
// ---------------------------------------------------------------------------
template<int BSRC, int NG, int EPI>
__global__ __launch_bounds__(256, 2) void gemm32t(
    const float* __restrict__ A0, const float* __restrict__ A1, int lda,
    const float* __restrict__ B0, const float* __restrict__ B1, int ldb,
    float* __restrict__ C0, float* __restrict__ C1,
    const float* __restrict__ bias0, const float* __restrict__ bias1,
    int N, int K, int nsplit, int MN)
{
    __shared__ f16 Al[128][40];
    __shared__ f16 Bl[128][40];
    const int t  = threadIdx.x;
    const int m0 = blockIdx.x * 128;
    const int n0 = blockIdx.y * 128;
    const int br = blockIdx.z / nsplit;
    const int s  = blockIdx.z % nsplit;
    const float* __restrict__ A = br ? A1 : A0;
    const float* __restrict__ B = br ? B1 : B0;
    float* __restrict__ C       = br ? C1 : C0;
    const float* __restrict__ bias = br ? bias1 : bias0;

    const int kchunk = ((K + nsplit * 32 - 1) / (nsplit * 32)) * 32;
    const int kb = s * kchunk;
    const int ke = min(K, kb + kchunk);

    const int sr_ = t >> 4;          // staging row-in-pass 0..15
    const int sc  = (t & 15) * 2;    // staging col pair 0..30
    const int bn  = t & 127;         // B transpose staging n
    const int bk2 = (t >> 7) * 16;   // B staging k-half base 0/16

    const int lane = t & 63, w = t >> 6;
    const int wr = (w >> 1) * 64, wc = (w & 1) * 64;
    const int fr = lane & 15, kg = (lane >> 4) * 8;

    f32x4 acc[4][4] = {};

    float2 ra[8];
    float  rb[16];
    float2 rb2[8];

    union U8 { f16x8 v; f16x2 h[4]; };

    auto loadA = [&](int k0, int krem) {
        #pragma unroll
        for (int p = 0; p < 8; p++) {
            const int row = p * 16 + sr_;
            float2 u = {0.f, 0.f};
            if (sc < krem) u = *(const float2*)(A + (size_t)(m0 + row) * lda + k0 + sc);
            ra[p] = u;
        }
    };
    auto loadB = [&](int k0, int krem) {
        if (BSRC == 0) {
            const bool nok = (!NG) || (n0 + bn < N);
            #pragma unroll
            for (int p = 0; p < 16; p++) {
                const int kk = bk2 + p;
                float x = 0.f;
                if (kk < krem && nok) x = B[(size_t)(k0 + kk) * ldb + n0 + bn];
                rb[p] = x;
            }
        } else {
            #pragma unroll
            for (int p = 0; p < 8; p++) {
                const int row = p * 16 + sr_;
                float2 u = {0.f, 0.f};
                if (sc < krem) u = *(const float2*)(B + (size_t)(n0 + row) * ldb + k0 + sc);
                rb2[p] = u;
            }
        }
    };
    auto storeA = [&]() {
        #pragma unroll
        for (int p = 0; p < 8; p++)
            *(f16x2*)&Al[p * 16 + sr_][sc] = pkh(ra[p].x, ra[p].y);
    };
    auto storeB = [&]() {
        if (BSRC == 0) {
            U8 u0, u1;
            u0.h[0] = pkh(rb[0],  rb[1]);
            u0.h[1] = pkh(rb[2],  rb[3]);
            u0.h[2] = pkh(rb[4],  rb[5]);
            u0.h[3] = pkh(rb[6],  rb[7]);
            u1.h[0] = pkh(rb[8],  rb[9]);
            u1.h[1] = pkh(rb[10], rb[11]);
            u1.h[2] = pkh(rb[12], rb[13]);
            u1.h[3] = pkh(rb[14], rb[15]);
            *(f16x8*)&Bl[bn][bk2]     = u0.v;
            *(f16x8*)&Bl[bn][bk2 + 8] = u1.v;
        } else {
            #pragma unroll
            for (int p = 0; p < 8; p++)
                *(f16x2*)&Bl[p * 16 + sr_][sc] = pkh(rb2[p].x, rb2[p].y);
        }
    };

    int k0 = kb;
    {
        const int kr = min(32, ke - k0);
        loadA(k0, kr); loadB(k0, kr);
    }
    while (k0 < ke) {
        storeA(); storeB();
        __syncthreads();
        const int k1 = k0 + 32;
        if (k1 < ke) {                       // prefetch next tile into regs
            const int kr = min(32, ke - k1);
            loadA(k1, kr); loadB(k1, kr);
        }
        f16x8 af[4], bf[4];
        #pragma unroll
        for (int m = 0; m < 4; m++) af[m] = *(const f16x8*)&Al[wr + m * 16 + fr][kg];
        #pragma unroll
        for (int n = 0; n < 4; n++) bf[n] = *(const f16x8*)&Bl[wc + n * 16 + fr][kg];
        #pragma unroll
        for (int m = 0; m < 4; m++)
            #pragma unroll
            for (int n = 0; n < 4; n++)
                acc[m][n] = __builtin_amdgcn_mfma_f32_16x16x32_f16(af[m], bf[n], acc[m][n], 0, 0, 0);
        __syncthreads();
        k0 = k1;
    }

    float* Cp = (EPI == 0) ? (C + (size_t)s * MN) : C;
    #pragma unroll
    for (int m = 0; m < 4; m++) {
        #pragma unroll
        for (int n = 0; n < 4; n++) {
            #pragma unroll
            for (int j = 0; j < 4; j++) {
                const int row = m0 + wr + m * 16 + (lane >> 4) * 4 + j;
                const int col = n0 + wc + n * 16 + fr;
                if (NG && col >= N) continue;
                if (EPI == 0) Cp[(size_t)row * N + col] = acc[m][n][j];
                else          Cp[(size_t)row * N + col] = softplus_f(acc[m][n][j] + bias[col]);
            }
        }
    }
}

// dual-branch split-K reduce + bias + exact GELU
__global__ __launch_bounds__(256) void reduce_bias_gelu2(
    const float* __restrict__ P0, const float* __restrict__ P1,
    const float* __restrict__ bias0, const float* __restrict__ bias1,
    float* __restrict__ H0, float* __restrict__ H1,
    int MN, int N, int nsplit)
{
    const int idx = blockIdx.x * 256 + threadIdx.x;
    if (idx >= MN) return;
    const int n = idx % N;
    const float* P = blockIdx.y ? P1 : P0;
    const float* bias = blockIdx.y ? bias1 : bias0;
    float* H = blockIdx.y ? H1 : H0;
    float s = 0.f;
    for (int k = 0; k < nsplit; k++) s += P[(size_t)k * MN + idx];
    H[idx] = gelu_exact(s + bias[n]);
}

__global__ __launch_bounds__(256) void reduce_sum_parts(
    const float* __restrict__ P, float* __restrict__ Y, int MN, int nsplit)
{
    const int idx = blockIdx.x * 256 + threadIdx.x;
    if (idx >= MN) return;
    float s = 0.f;
    for (int k = 0; k < nsplit; k++) s += P[(size_t)k * MN + idx];
    Y[idx] = s;
}

// ---------------------------------------------------------------------------
// Exact per-row K-th-largest via 12/12/7-bit radix select on float bits.
// ---------------------------------------------------------------------------
__global__ __launch_bounds__(TKT) void topk_thresh2(
    const float* __restrict__ U1, const float* __restrict__ U2,
    float* __restrict__ tP, float* __restrict__ tM)
{
    __shared__ unsigned int hist[4096];
    __shared__ unsigned int scan[TKT];
    __shared__ unsigned int s_pref;
    __shared__ int s_rem;
    const int row = blockIdx.y, t = threadIdx.x;
    const float* u = (blockIdx.x ? U2 : U1) + (size_t)row * VSZ;
    float* tout = blockIdx.x ? tM : tP;

    unsigned int pref = 0;
    int remain = KDELT;

    #pragma unroll
    for (int p = 0; p < 3; p++) {
        for (int i = t; i < 4096; i += TKT) hist[i] = 0;
        __syncthreads();
        for (int j = t; j < VSZ / 2; j += TKT) {
            const float2 x = *(const float2*)(u + 2 * j);
            const unsigned int v0 = __float_as_uint(x.x);
            const unsigned int v1 = __float_as_uint(x.y);
            if (p == 0) {
                atomicAdd(&hist[v0 >> 19], 1u);
                atomicAdd(&hist[v1 >> 19], 1u);
            } else if (p == 1) {
                if ((v0 >> 19) == pref) atomicAdd(&hist[(v0 >> 7) & 0xFFFu], 1u);
                if ((v1 >> 19) == pref) atomicAdd(&hist[(v1 >> 7) & 0xFFFu], 1u);
            } else {
                if ((v0 >> 7) == pref) atomicAdd(&hist[v0 & 0x7Fu], 1u);
                if ((v1 >> 7) == pref) atomicAdd(&hist[v1 & 0x7Fu], 1u);
            }
        }
        __syncthreads();
        // suffix scan: thread t owns bins [4t, 4t+4)
        unsigned int loc = hist[4 * t] + hist[4 * t + 1] + hist[4 * t + 2] + hist[4 * t + 3];
        scan[t] = loc;
        __syncthreads();
        for (int o = 1; o < TKT; o <<= 1) {
            const unsigned int v = (t + o < TKT) ? scan[t + o] : 0u;
            __syncthreads();
            scan[t] += v;
            __syncthreads();
        }
        const unsigned int above = (t + 1 < TKT) ? scan[t + 1] : 0u;
        if (scan[t] >= (unsigned int)remain && above < (unsigned int)remain) {
            unsigned int cum = above;
            #pragma unroll
            for (int bi = 3; bi >= 0; bi--) {
                const int b = 4 * t + bi;
                cum += hist[b];
                if (cum >= (unsigned int)remain) {
                    s_pref = (unsigned int)b;
                    s_rem  = remain - (int)(cum - hist[b]);
                    break;
                }
            }
        }
        __syncthreads();
        if (p == 0)      pref = s_pref;
        else if (p == 1) pref = (pref << 12) | s_pref;
        else             pref = (pref << 7)  | s_pref;
        remain = s_rem;
        __syncthreads();
    }
    if (t == 0) tout[row] = __uint_as_float(pref);
}

// U1 := clip(sr + dsp,0) - clip(dsm,0); row-sums of dsp/dsm for loss_sparse.
__global__ __launch_bounds__(256) void build_sq(
    float* __restrict__ U1, const float* __restrict__ U2,
    const float* __restrict__ sr,
    const float* __restrict__ tp, const float* __restrict__ tm,
    float* __restrict__ sparse_p, float* __restrict__ sparse_m)
{
    __shared__ float red[256];
    const int row = blockIdx.x, t = threadIdx.x;
    const float thp = tp[row], thm = tm[row];
    float* u1 = U1 + (size_t)row * VSZ;
    const float* u2 = U2 + (size_t)row * VSZ;
    const float* s  = sr + (size_t)row * VSZ;
    float sp = 0.f, sm = 0.f;
    for (int j = t; j < VSZ / 2; j += 256) {
        const float2 up = *(const float2*)(u1 + 2 * j);
        const float2 um = *(const float2*)(u2 + 2 * j);
        const float2 ss = *(const float2*)(s  + 2 * j);
        const float dp0 = (up.x >= thp) ? up.x : 0.f;
        const float dp1 = (up.y >= thp) ? up.y : 0.f;
        const float dm0 = (um.x >= thm) ? um.x : 0.f;
        const float dm1 = (um.y >= thm) ? um.y : 0.f;
        sp += dp0 + dp1; sm += dm0 + dm1;
        float2 o;
        o.x = fmaxf(ss.x + dp0, 0.f) - fmaxf(dm0, 0.f);
        o.y = fmaxf(ss.y + dp1, 0.f) - fmaxf(dm1, 0.f);
        *(float2*)(u1 + 2 * j) = o;
    }
    red[t] = sp; __syncthreads();
    for (int o = 128; o > 0; o >>= 1) { if (t < o) red[t] += red[t + o]; __syncthreads(); }
    if (t == 0) sparse_p[row] = red[0];
    __syncthreads();
    red[t] = sm; __syncthreads();
    for (int o = 128; o > 0; o >>= 1) { if (t < o) red[t] += red[t + o]; __syncthreads(); }
    if (t == 0) sparse_m[row] = red[0];
}

__global__ __launch_bounds__(256) void rownorm(
    const float* __restrict__ X, float* __restrict__ Y, int dbl)
{
    __shared__ float red[256];
    const int row = blockIdx.x, t = threadIdx.x;
    const float* x = X + (size_t)row * DIM;
    float* y = Y + (size_t)row * DIM;
    float v0 = x[t], v1 = x[t + 256], v2 = x[t + 512];
    red[t] = v0 * v0 + v1 * v1 + v2 * v2; __syncthreads();
    for (int o = 128; o > 0; o >>= 1) { if (t < o) red[t] += red[t + o]; __syncthreads(); }
    const float nrm = sqrtf(red[0]) + EPSN;
    v0 /= nrm; v1 /= nrm; v2 /= nrm;
    if (dbl) {
        __syncthreads();
        red[t] = v0 * v0 + v1 * v1 + v2 * v2; __syncthreads();
        for (int o = 128; o > 0; o >>= 1) { if (t < o) red[t] += red[t + o]; __syncthreads(); }
        const float n2 = sqrtf(red[0]) + EPSN;
        v0 /= n2; v1 /= n2; v2 /= n2;
    }
    y[t] = v0; y[t + 256] = v1; y[t + 512] = v2;
}

__global__ __launch_bounds__(256) void pos_dot(
    const float* __restrict__ zq, const float* __restrict__ zp,
    float* __restrict__ posL)
{
    __shared__ float red[256];
    const int row = blockIdx.x, t = threadIdx.x;
    const float* a = zq + (size_t)row * DIM;
    const float* b = zp + (size_t)row * DIM;
    red[t] = a[t] * b[t] + a[t + 256] * b[t + 256] + a[t + 512] * b[t + 512];
    __syncthreads();
    for (int o = 128; o > 0; o >>= 1) { if (t < o) red[t] += red[t + o]; __syncthreads(); }
    if (t == 0) posL[row] = red[0] / TEMPC;
}

// NegL holds raw dot products; scale by 1/TEMP here.
__global__ __launch_bounds__(256) void lse_loss(
    const float* __restrict__ negL, const float* __restrict__ posL,
    float* __restrict__ rowL)
{
    __shared__ float red[256];
    const int row = blockIdx.x, t = threadIdx.x;
    const float* nl = negL + (size_t)row * MNEG;
    const float p = posL[row];
    float lmax = (t == 0) ? p : -INFINITY;
    for (int j = t; j < MNEG; j += 256) lmax = fmaxf(lmax, nl[j] * INVT);
    red[t] = lmax; __syncthreads();
    for (int o = 128; o > 0; o >>= 1) { if (t < o) red[t] = fmaxf(red[t], red[t + o]); __syncthreads(); }
    const float mx = red[0];
    __syncthreads();
    float lsum = (t == 0) ? expf(p - mx) : 0.f;
    for (int j = t; j < MNEG; j += 256) lsum += expf(nl[j] * INVT - mx);
    red[t] = lsum; __syncthreads();
    for (int o = 128; o > 0; o >>= 1) { if (t < o) red[t] += red[t + o]; __syncthreads(); }
    if (t == 0) rowL[row] = mx + logf(red[0]) - p;
}

__global__ __launch_bounds__(256) void rec_row(
    const float* __restrict__ zhat, const float* __restrict__ zrn,
    float* __restrict__ part)
{
    __shared__ float red[256];
    const int row = blockIdx.x, t = threadIdx.x;
    const float* a = zhat + (size_t)row * DIM;
    const float* b = zrn + (size_t)row * DIM;
    const float d0 = a[t] - b[t], d1 = a[t + 256] - b[t + 256], d2 = a[t + 512] - b[t + 512];
    red[t] = d0 * d0 + d1 * d1 + d2 * d2;
    __syncthreads();
    for (int o = 128; o > 0; o >>= 1) { if (t < o) red[t] += red[t + o]; __syncthreads(); }
    if (t == 0) part[row] = red[0];
}

__global__ __launch_bounds__(256) void final_combine(
    const float* __restrict__ rowL, const float* __restrict__ recP,
    const float* __restrict__ spP, const float* __restrict__ spM,
    float* __restrict__ out)
{
    __shared__ float red[256];
    const int t = threadIdx.x;
    red[t] = rowL[t]; __syncthreads();
    for (int o = 128; o > 0; o >>= 1) { if (t < o) red[t] += red[t + o]; __syncthreads(); }
    const float retr = red[0] / 256.0f;
    __syncthreads();
    red[t] = recP[t]; __syncthreads();
    for (int o = 128; o > 0; o >>= 1) { if (t < o) red[t] += red[t + o]; __syncthreads(); }
    const float rec = red[0] / (float)(BATCH * DIM);
    __syncthreads();
    red[t] = spP[t] + spM[t]; __syncthreads();
    for (int o = 128; o > 0; o >>= 1) { if (t < o) red[t] += red[t + o]; __syncthreads(); }
    const float sparse = red[0] / 256.0f;
    if (t == 0) out[0] = retr + 1.0f * rec + 1e-4f * sparse;
}

extern "C" void kernel_launch(void* const* d_in, const int* in_sizes, int n_in,
                              void* d_out, int out_size, void* d_ws, size_t ws_size,
                              hipStream_t stream)
{
    const float* ht   = (const float*)d_in[0];
    const float* sr   = (const float*)d_in[1];
    const float* zpos = (const float*)d_in[2];
    const float* zneg = (const float*)d_in[3];
    const float* zr   = (const float*)d_in[4];
    const float* W1p  = (const float*)d_in[5];
    const float* b1p  = (const float*)d_in[6];
    const float* W2p  = (const float*)d_in[7];
    const float* b2p  = (const float*)d_in[8];
    const float* W1m  = (const float*)d_in[9];
    const float* b1m  = (const float*)d_in[10];
    const float* W2m  = (const float*)d_in[11];
    const float* b2m  = (const float*)d_in[12];
    const float* Wdec = (const float*)d_in[13];
    float* out = (float*)d_out;

    // workspace layout (bytes)
    char* ws = (char*)d_ws;
    float* U1   = (float*)(ws + 0);            // 31,254,528 (u_p -> sq)
    float* U2   = (float*)(ws + 31254528);     // 31,254,528 (u_m; dead after build_sq ->
                                               //   reused as decode branch-m partials, 25.2 MB)
    float* P    = (float*)(ws + 62509056);     // 33,554,432 partial arena (serial reuse)
    float* P1g  = (float*)(ws + 62509056 + 16777216);  // gemm1 branch-m partials
    float* Hp   = (float*)(ws + 96063488);     //      524,288
    float* Hm   = (float*)(ws + 96587776);     //      524,288
    float* Y1   = (float*)(ws + 97112064);     //      786,432
    float* Y2   = (float*)(ws + 97898496);     //      786,432
    float* Zn   = (float*)(ws + 98684928);     //   12,582,912
    float* Zp   = (float*)(ws + 111267840);    //      786,432
    float* Zrn  = (float*)(ws + 112054272);    //      786,432
    float* NegL = (float*)(ws + 112840704);    //    4,194,304
    float* tP   = (float*)(ws + 117035008);    // small vectors (256 floats each)
    float* tM   = tP + 256;
    float* spP  = tP + 512;
    float* spM  = tP + 768;
    float* posL = tP + 1024;
    float* rowL = tP + 1280;
    float* recP = tP + 1536;
    (void)in_sizes; (void)n_in; (void)out_size; (void)ws_size;

    const dim3 blk(256);

    // ---- GEMM1 dual (ht@W1p | ht@W1m), split-K 32 each, grid 512 blocks
    gemm32t<0,0,0><<<dim3(2,4,64), blk, 0, stream>>>(
        ht, ht, VSZ, W1p, W1m, BOT, P, P1g, nullptr, nullptr,
        BOT, VSZ, 32, BATCH*BOT);
    reduce_bias_gelu2<<<dim3(512,2), blk, 0, stream>>>(
        P, P1g, b1p, b1m, Hp, Hm, BATCH*BOT, BOT, 32);

    // ---- GEMM2 dual (Hp@W2p | Hm@W2m), fused softplus+bias, grid 956 blocks
    gemm32t<0,1,1><<<dim3(2,239,2), blk, 0, stream>>>(
        Hp, Hm, BOT, W2p, W2m, VSZ, U1, U2, b2p, b2m,
        VSZ, BOT, 1, 0);

    // ---- exact top-K thresholds (both branches, one launch)
    topk_thresh2<<<dim3(2,256), dim3(TKT), 0, stream>>>(U1, U2, tP, tM);
    build_sq<<<dim3(256), blk, 0, stream>>>(U1, U2, sr, tP, tM, spP, spM);

    // ---- decode dual (sq@Wdec | sr@Wdec), split-K 32, grid 768 blocks (3/CU)
    //      branch-p partials -> P, branch-m partials -> dead U2 region
    gemm32t<0,0,0><<<dim3(2,6,64), blk, 0, stream>>>(
        U1, sr, VSZ, Wdec, Wdec, DIM, P, U2, nullptr, nullptr,
        DIM, VSZ, 32, BATCH*DIM);
    reduce_sum_parts<<<dim3(768), blk, 0, stream>>>(P,  Y1, BATCH*DIM, 32);
    reduce_sum_parts<<<dim3(768), blk, 0, stream>>>(U2, Y2, BATCH*DIM, 32);

    // ---- normalizations
    rownorm<<<dim3(256),  blk, 0, stream>>>(Y1, Y1, 1);   // zq (double norm)
    rownorm<<<dim3(256),  blk, 0, stream>>>(Y2, Y2, 0);   // zhat_r
    rownorm<<<dim3(4096), blk, 0, stream>>>(zneg, Zn, 0);
    rownorm<<<dim3(256),  blk, 0, stream>>>(zpos, Zp, 0);
    rownorm<<<dim3(256),  blk, 0, stream>>>(zr,   Zrn, 0);

    // ---- retrieval loss
    pos_dot<<<dim3(256), blk, 0, stream>>>(Y1, Zp, posL);
    gemm32t<1,0,0><<<dim3(2,32,4), blk, 0, stream>>>(
        Y1, Y1, DIM, Zn, Zn, DIM, P, P, nullptr, nullptr,
        MNEG, DIM, 4, BATCH*MNEG);
    reduce_sum_parts<<<dim3(4096), blk, 0, stream>>>(P, NegL, BATCH*MNEG, 4);
    lse_loss<<<dim3(256), blk, 0, stream>>>(NegL, posL, rowL);

    // ---- reconstruction loss
    rec_row<<<dim3(256), blk, 0, stream>>>(Y2, Zrn, recP);

    // ---- combine
    final_combine<<<dim3(1), blk, 0, stream>>>(rowL, recP, spP, spM, out);
}

// Round 8
// 423.842 us; speedup vs baseline: 5.4525x; 1.0087x over previous
//
#include <hip/hip_runtime.h>
#include <math.h>

#define VSZ   30522
#define DIM   768
#define KDELT 768
#define BOT   512
#define BATCH 256
#define MNEG  4096
#define EPSN  1e-6f
#define TEMPC 0.05f
#define INVT  20.0f
#define TKT   1024

typedef _Float16 f16;
typedef _Float16 f16x8 __attribute__((ext_vector_type(8)));
typedef _Float16 f16x2 __attribute__((ext_vector_type(2)));
typedef float    f32x4 __attribute__((ext_vector_type(4)));

static __device__ __forceinline__ float gelu_exact(float x){
    return 0.5f * x * (1.0f + erff(x * 0.70710678118654752440f));
}
static __device__ __forceinline__ float softplus_f(float x){
    return fmaxf(x, 0.0f) + log1pf(expf(-fabsf(x)));
}
static __device__ __forceinline__ f16x2 pkh(float a, float b){
    return __builtin_bit_cast(f16x2, __builtin_amdgcn_cvt_pkrtz(a, b));
}

// ---------------------------------------------------------------------------
// fp32-in / fp16-MFMA GEMM. R7: ALL dims compile-time (LDA/LDB/N/K/NSPLIT) —
// round-7 counters showed VALUBusy 57% / MfmaUtil 5.4% unchanged by LDS fixes;
// the VALU load is ~100 addr-arith ops/K-step from runtime strides. With
// template dims the compiler hoists per-thread offsets and strength-reduces
// the k-advance to literal adds. A/B2 staging now 4x dwordx4 + 2x ds_write_b128.
// Register-batched staging + next-tile prefetch (T14) as before.
// ---------------------------------------------------------------------------
template<int BSRC, int NG, int EPI, int LDA, int LDB, int N, int K, int NSPLIT>
__global__ __launch_bounds__(256, 2) void gemm32t(
    const float* __restrict__ A0, const float* __restrict__ A1,
    const float* __restrict__ B0, const float* __restrict__ B1,
    float* __restrict__ C0, float* __restrict__ C1,
    const float* __restrict__ bias0, const float* __restrict__ bias1)
{
    constexpr int MN = BATCH * N;
    __shared__ f16 Al[128][40];
    __shared__ f16 Bl[128][40];
    const int t  = threadIdx.x;
    const int m0 = blockIdx.x * 128;
    const int n0 = blockIdx.y * 128;
    const int br = blockIdx.z / NSPLIT;
    const int s  = blockIdx.z % NSPLIT;
    const float* __restrict__ A = br ? A1 : A0;
    const float* __restrict__ B = br ? B1 : B0;
    float* __restrict__ C       = br ? C1 : C0;
    const float* __restrict__ bias = br ? bias1 : bias0;

    constexpr int kchunk = ((K + NSPLIT * 32 - 1) / (NSPLIT * 32)) * 32;
    const int kb = s * kchunk;
    const int ke = min(K, kb + kchunk);

    const int ar4 = t >> 2;          // A/B2 staging row 0..63 (two passes)
    const int kq  = (t & 3) * 8;     // k-octet base 0,8,16,24
    const int bn  = t & 127;         // B transpose staging n
    const int bk2 = (t >> 7) * 16;   // B staging k-half base 0/16

    const int lane = t & 63, w = t >> 6;
    const int wr = (w >> 1) * 64, wc = (w & 1) * 64;
    const int fr = lane & 15, kg = (lane >> 4) * 8;

    f32x4 acc[4][4] = {};

    float4 ra[2][2];
    float  rb[16];
    float4 rb2[2][2];

    union U8 { f16x8 v; f16x2 h[4]; };

    auto loadA = [&](int k0, int krem) {
        #pragma unroll
        for (int p = 0; p < 2; p++) {
            const float* ap = A + (size_t)(m0 + p * 64 + ar4) * LDA + k0 + kq;
            if (kq + 8 <= krem) {
                ra[p][0] = *(const float4*)ap;
                ra[p][1] = *(const float4*)(ap + 4);
            } else {
                float tm[8];
                #pragma unroll
                for (int i = 0; i < 8; i++) tm[i] = (kq + i < krem) ? ap[i] : 0.f;
                ra[p][0] = make_float4(tm[0], tm[1], tm[2], tm[3]);
                ra[p][1] = make_float4(tm[4], tm[5], tm[6], tm[7]);
            }
        }
    };
    auto loadB = [&](int k0, int krem) {
        if (BSRC == 0) {
            const bool nok = (!NG) || (n0 + bn < N);
            #pragma unroll
            for (int p = 0; p < 16; p++) {
                const int kk = bk2 + p;
                float x = 0.f;
                if (kk < krem && nok) x = B[(size_t)(k0 + kk) * LDB + n0 + bn];
                rb[p] = x;
            }
        } else {
            #pragma unroll
            for (int p = 0; p < 2; p++) {
                const float* bp = B + (size_t)(n0 + p * 64 + ar4) * LDB + k0 + kq;
                if (kq + 8 <= krem) {
                    rb2[p][0] = *(const float4*)bp;
                    rb2[p][1] = *(const float4*)(bp + 4);
                } else {
                    float tm[8];
                    #pragma unroll
                    for (int i = 0; i < 8; i++) tm[i] = (kq + i < krem) ? bp[i] : 0.f;
                    rb2[p][0] = make_float4(tm[0], tm[1], tm[2], tm[3]);
                    rb2[p][1] = make_float4(tm[4], tm[5], tm[6], tm[7]);
                }
            }
        }
    };
    auto storeA = [&]() {
        #pragma unroll
        for (int p = 0; p < 2; p++) {
            U8 u;
            u.h[0] = pkh(ra[p][0].x, ra[p][0].y);
            u.h[1] = pkh(ra[p][0].z, ra[p][0].w);
            u.h[2] = pkh(ra[p][1].x, ra[p][1].y);
            u.h[3] = pkh(ra[p][1].z, ra[p][1].w);
            *(f16x8*)&Al[p * 64 + ar4][kq] = u.v;
        }
    };
    auto storeB = [&]() {
        if (BSRC == 0) {
            U8 u0, u1;
            u0.h[0] = pkh(rb[0],  rb[1]);
            u0.h[1] = pkh(rb[2],  rb[3]);
            u0.h[2] = pkh(rb[4],  rb[5]);
            u0.h[3] = pkh(rb[6],  rb[7]);
            u1.h[0] = pkh(rb[8],  rb[9]);
            u1.h[1] = pkh(rb[10], rb[11]);
            u1.h[2] = pkh(rb[12], rb[13]);
            u1.h[3] = pkh(rb[14], rb[15]);
            *(f16x8*)&Bl[bn][bk2]     = u0.v;
            *(f16x8*)&Bl[bn][bk2 + 8] = u1.v;
        } else {
            #pragma unroll
            for (int p = 0; p < 2; p++) {
                U8 u;
                u.h[0] = pkh(rb2[p][0].x, rb2[p][0].y);
                u.h[1] = pkh(rb2[p][0].z, rb2[p][0].w);
                u.h[2] = pkh(rb2[p][1].x, rb2[p][1].y);
                u.h[3] = pkh(rb2[p][1].z, rb2[p][1].w);
                *(f16x8*)&Bl[p * 64 + ar4][kq] = u.v;
            }
        }
    };

    int k0 = kb;
    {
        const int kr = min(32, ke - k0);
        loadA(k0, kr); loadB(k0, kr);
    }
    while (k0 < ke) {
        storeA(); storeB();
        __syncthreads();
        const int k1 = k0 + 32;
        if (k1 < ke) {                       // prefetch next tile into regs
            const int kr = min(32, ke - k1);
            loadA(k1, kr); loadB(k1, kr);
        }
        f16x8 af[4], bf[4];
        #pragma unroll
        for (int m = 0; m < 4; m++) af[m] = *(const f16x8*)&Al[wr + m * 16 + fr][kg];
        #pragma unroll
        for (int n = 0; n < 4; n++) bf[n] = *(const f16x8*)&Bl[wc + n * 16 + fr][kg];
        #pragma unroll
        for (int m = 0; m < 4; m++)
            #pragma unroll
            for (int n = 0; n < 4; n++)
                acc[m][n] = __builtin_amdgcn_mfma_f32_16x16x32_f16(af[m], bf[n], acc[m][n], 0, 0, 0);
        __syncthreads();
        k0 = k1;
    }

    float* Cp = (EPI == 0) ? (C + (size_t)s * MN) : C;
    #pragma unroll
    for (int m = 0; m < 4; m++) {
        #pragma unroll
        for (int n = 0; n < 4; n++) {
            #pragma unroll
            for (int j = 0; j < 4; j++) {
                const int row = m0 + wr + m * 16 + (lane >> 4) * 4 + j;
                const int col = n0 + wc + n * 16 + fr;
                if (NG && col >= N) continue;
                if (EPI == 0) Cp[(size_t)row * N + col] = acc[m][n][j];
                else          Cp[(size_t)row * N + col] = softplus_f(acc[m][n][j] + bias[col]);
            }
        }
    }
}

// dual-branch split-K reduce + bias + exact GELU
__global__ __launch_bounds__(256) void reduce_bias_gelu2(
    const float* __restrict__ P0, const float* __restrict__ P1,
    const float* __restrict__ bias0, const float* __restrict__ bias1,
    float* __restrict__ H0, float* __restrict__ H1,
    int MN, int N, int nsplit)
{
    const int idx = blockIdx.x * 256 + threadIdx.x;
    if (idx >= MN) return;
    const int n = idx % N;
    const float* P = blockIdx.y ? P1 : P0;
    const float* bias = blockIdx.y ? bias1 : bias0;
    float* H = blockIdx.y ? H1 : H0;
    float s = 0.f;
    for (int k = 0; k < nsplit; k++) s += P[(size_t)k * MN + idx];
    H[idx] = gelu_exact(s + bias[n]);
}

__global__ __launch_bounds__(256) void reduce_sum_parts(
    const float* __restrict__ P, float* __restrict__ Y, int MN, int nsplit)
{
    const int idx = blockIdx.x * 256 + threadIdx.x;
    if (idx >= MN) return;
    float s = 0.f;
    for (int k = 0; k < nsplit; k++) s += P[(size_t)k * MN + idx];
    Y[idx] = s;
}

// ---------------------------------------------------------------------------
// Exact per-row K-th-largest via 12/12/7-bit radix select on float bits.
// ---------------------------------------------------------------------------
__global__ __launch_bounds__(TKT) void topk_thresh2(
    const float* __restrict__ U1, const float* __restrict__ U2,
    float* __restrict__ tP, float* __restrict__ tM)
{
    __shared__ unsigned int hist[4096];
    __shared__ unsigned int scan[TKT];
    __shared__ unsigned int s_pref;
    __shared__ int s_rem;
    const int row = blockIdx.y, t = threadIdx.x;
    const float* u = (blockIdx.x ? U2 : U1) + (size_t)row * VSZ;
    float* tout = blockIdx.x ? tM : tP;

    unsigned int pref = 0;
    int remain = KDELT;

    #pragma unroll
    for (int p = 0; p < 3; p++) {
        for (int i = t; i < 4096; i += TKT) hist[i] = 0;
        __syncthreads();
        for (int j = t; j < VSZ / 2; j += TKT) {
            const float2 x = *(const float2*)(u + 2 * j);
            const unsigned int v0 = __float_as_uint(x.x);
            const unsigned int v1 = __float_as_uint(x.y);
            if (p == 0) {
                atomicAdd(&hist[v0 >> 19], 1u);
                atomicAdd(&hist[v1 >> 19], 1u);
            } else if (p == 1) {
                if ((v0 >> 19) == pref) atomicAdd(&hist[(v0 >> 7) & 0xFFFu], 1u);
                if ((v1 >> 19) == pref) atomicAdd(&hist[(v1 >> 7) & 0xFFFu], 1u);
            } else {
                if ((v0 >> 7) == pref) atomicAdd(&hist[v0 & 0x7Fu], 1u);
                if ((v1 >> 7) == pref) atomicAdd(&hist[v1 & 0x7Fu], 1u);
            }
        }
        __syncthreads();
        // suffix scan: thread t owns bins [4t, 4t+4)
        unsigned int loc = hist[4 * t] + hist[4 * t + 1] + hist[4 * t + 2] + hist[4 * t + 3];
        scan[t] = loc;
        __syncthreads();
        for (int o = 1; o < TKT; o <<= 1) {
            const unsigned int v = (t + o < TKT) ? scan[t + o] : 0u;
            __syncthreads();
            scan[t] += v;
            __syncthreads();
        }
        const unsigned int above = (t + 1 < TKT) ? scan[t + 1] : 0u;
        if (scan[t] >= (unsigned int)remain && above < (unsigned int)remain) {
            unsigned int cum = above;
            #pragma unroll
            for (int bi = 3; bi >= 0; bi--) {
                const int b = 4 * t + bi;
                cum += hist[b];
                if (cum >= (unsigned int)remain) {
                    s_pref = (unsigned int)b;
                    s_rem  = remain - (int)(cum - hist[b]);
                    break;
                }
            }
        }
        __syncthreads();
        if (p == 0)      pref = s_pref;
        else if (p == 1) pref = (pref << 12) | s_pref;
        else             pref = (pref << 7)  | s_pref;
        remain = s_rem;
        __syncthreads();
    }
    if (t == 0) tout[row] = __uint_as_float(pref);
}

// U1 := clip(sr + dsp,0) - clip(dsm,0); row-sums of dsp/dsm for loss_sparse.
__global__ __launch_bounds__(256) void build_sq(
    float* __restrict__ U1, const float* __restrict__ U2,
    const float* __restrict__ sr,
    const float* __restrict__ tp, const float* __restrict__ tm,
    float* __restrict__ sparse_p, float* __restrict__ sparse_m)
{
    __shared__ float red[256];
    const int row = blockIdx.x, t = threadIdx.x;
    const float thp = tp[row], thm = tm[row];
    float* u1 = U1 + (size_t)row * VSZ;
    const float* u2 = U2 + (size_t)row * VSZ;
    const float* s  = sr + (size_t)row * VSZ;
    float sp = 0.f, sm = 0.f;
    for (int j = t; j < VSZ / 2; j += 256) {
        const float2 up = *(const float2*)(u1 + 2 * j);
        const float2 um = *(const float2*)(u2 + 2 * j);
        const float2 ss = *(const float2*)(s  + 2 * j);
        const float dp0 = (up.x >= thp) ? up.x : 0.f;
        const float dp1 = (up.y >= thp) ? up.y : 0.f;
        const float dm0 = (um.x >= thm) ? um.x : 0.f;
        const float dm1 = (um.y >= thm) ? um.y : 0.f;
        sp += dp0 + dp1; sm += dm0 + dm1;
        float2 o;
        o.x = fmaxf(ss.x + dp0, 0.f) - fmaxf(dm0, 0.f);
        o.y = fmaxf(ss.y + dp1, 0.f) - fmaxf(dm1, 0.f);
        *(float2*)(u1 + 2 * j) = o;
    }
    red[t] = sp; __syncthreads();
    for (int o = 128; o > 0; o >>= 1) { if (t < o) red[t] += red[t + o]; __syncthreads(); }
    if (t == 0) sparse_p[row] = red[0];
    __syncthreads();
    red[t] = sm; __syncthreads();
    for (int o = 128; o > 0; o >>= 1) { if (t < o) red[t] += red[t + o]; __syncthreads(); }
    if (t == 0) sparse_m[row] = red[0];
}

__global__ __launch_bounds__(256) void rownorm(
    const float* __restrict__ X, float* __restrict__ Y, int dbl)
{
    __shared__ float red[256];
    const int row = blockIdx.x, t = threadIdx.x;
    const float* x = X + (size_t)row * DIM;
    float* y = Y + (size_t)row * DIM;
    float v0 = x[t], v1 = x[t + 256], v2 = x[t + 512];
    red[t] = v0 * v0 + v1 * v1 + v2 * v2; __syncthreads();
    for (int o = 128; o > 0; o >>= 1) { if (t < o) red[t] += red[t + o]; __syncthreads(); }
    const float nrm = sqrtf(red[0]) + EPSN;
    v0 /= nrm; v1 /= nrm; v2 /= nrm;
    if (dbl) {
        __syncthreads();
        red[t] = v0 * v0 + v1 * v1 + v2 * v2; __syncthreads();
        for (int o = 128; o > 0; o >>= 1) { if (t < o) red[t] += red[t + o]; __syncthreads(); }
        const float n2 = sqrtf(red[0]) + EPSN;
        v0 /= n2; v1 /= n2; v2 /= n2;
    }
    y[t] = v0; y[t + 256] = v1; y[t + 512] = v2;
}

__global__ __launch_bounds__(256) void pos_dot(
    const float* __restrict__ zq, const float* __restrict__ zp,
    float* __restrict__ posL)
{
    __shared__ float red[256];
    const int row = blockIdx.x, t = threadIdx.x;
    const float* a = zq + (size_t)row * DIM;
    const float* b = zp + (size_t)row * DIM;
    red[t] = a[t] * b[t] + a[t + 256] * b[t + 256] + a[t + 512] * b[t + 512];
    __syncthreads();
    for (int o = 128; o > 0; o >>= 1) { if (t < o) red[t] += red[t + o]; __syncthreads(); }
    if (t == 0) posL[row] = red[0] / TEMPC;
}

// NegL holds raw dot products; scale by 1/TEMP here.
__global__ __launch_bounds__(256) void lse_loss(
    const float* __restrict__ negL, const float* __restrict__ posL,
    float* __restrict__ rowL)
{
    __shared__ float red[256];
    const int row = blockIdx.x, t = threadIdx.x;
    const float* nl = negL + (size_t)row * MNEG;
    const float p = posL[row];
    float lmax = (t == 0) ? p : -INFINITY;
    for (int j = t; j < MNEG; j += 256) lmax = fmaxf(lmax, nl[j] * INVT);
    red[t] = lmax; __syncthreads();
    for (int o = 128; o > 0; o >>= 1) { if (t < o) red[t] = fmaxf(red[t], red[t + o]); __syncthreads(); }
    const float mx = red[0];
    __syncthreads();
    float lsum = (t == 0) ? expf(p - mx) : 0.f;
    for (int j = t; j < MNEG; j += 256) lsum += expf(nl[j] * INVT - mx);
    red[t] = lsum; __syncthreads();
    for (int o = 128; o > 0; o >>= 1) { if (t < o) red[t] += red[t + o]; __syncthreads(); }
    if (t == 0) rowL[row] = mx + logf(red[0]) - p;
}

__global__ __launch_bounds__(256) void rec_row(
    const float* __restrict__ zhat, const float* __restrict__ zrn,
    float* __restrict__ part)
{
    __shared__ float red[256];
    const int row = blockIdx.x, t = threadIdx.x;
    const float* a = zhat + (size_t)row * DIM;
    const float* b = zrn + (size_t)row * DIM;
    const float d0 = a[t] - b[t], d1 = a[t + 256] - b[t + 256], d2 = a[t + 512] - b[t + 512];
    red[t] = d0 * d0 + d1 * d1 + d2 * d2;
    __syncthreads();
    for (int o = 128; o > 0; o >>= 1) { if (t < o) red[t] += red[t + o]; __syncthreads(); }
    if (t == 0) part[row] = red[0];
}

__global__ __launch_bounds__(256) void final_combine(
    const float* __restrict__ rowL, const float* __restrict__ recP,
    const float* __restrict__ spP, const float* __restrict__ spM,
    float* __restrict__ out)
{
    __shared__ float red[256];
    const int t = threadIdx.x;
    red[t] = rowL[t]; __syncthreads();
    for (int o = 128; o > 0; o >>= 1) { if (t < o) red[t] += red[t + o]; __syncthreads(); }
    const float retr = red[0] / 256.0f;
    __syncthreads();
    red[t] = recP[t]; __syncthreads();
    for (int o = 128; o > 0; o >>= 1) { if (t < o) red[t] += red[t + o]; __syncthreads(); }
    const float rec = red[0] / (float)(BATCH * DIM);
    __syncthreads();
    red[t] = spP[t] + spM[t]; __syncthreads();
    for (int o = 128; o > 0; o >>= 1) { if (t < o) red[t] += red[t + o]; __syncthreads(); }
    const float sparse = red[0] / 256.0f;
    if (t == 0) out[0] = retr + 1.0f * rec + 1e-4f * sparse;
}

extern "C" void kernel_launch(void* const* d_in, const int* in_sizes, int n_in,
                              void* d_out, int out_size, void* d_ws, size_t ws_size,
                              hipStream_t stream)
{
    const float* ht   = (const float*)d_in[0];
    const float* sr   = (const float*)d_in[1];
    const float* zpos = (const float*)d_in[2];
    const float* zneg = (const float*)d_in[3];
    const float* zr   = (const float*)d_in[4];
    const float* W1p  = (const float*)d_in[5];
    const float* b1p  = (const float*)d_in[6];
    const float* W2p  = (const float*)d_in[7];
    const float* b2p  = (const float*)d_in[8];
    const float* W1m  = (const float*)d_in[9];
    const float* b1m  = (const float*)d_in[10];
    const float* W2m  = (const float*)d_in[11];
    const float* b2m  = (const float*)d_in[12];
    const float* Wdec = (const float*)d_in[13];
    float* out = (float*)d_out;

    // workspace layout (bytes)
    char* ws = (char*)d_ws;
    float* U1   = (float*)(ws + 0);            // 31,254,528 (u_p -> sq)
    float* U2   = (float*)(ws + 31254528);     // 31,254,528 (u_m; dead after build_sq ->
                                               //   reused as decode branch-m partials)
    float* P    = (float*)(ws + 62509056);     // 33,554,432 partial arena (serial reuse)
    float* P1g  = (float*)(ws + 62509056 + 16777216);  // gemm1 branch-m partials
    float* Hp   = (float*)(ws + 96063488);     //      524,288
    float* Hm   = (float*)(ws + 96587776);     //      524,288
    float* Y1   = (float*)(ws + 97112064);     //      786,432
    float* Y2   = (float*)(ws + 97898496);     //      786,432
    float* Zn   = (float*)(ws + 98684928);     //   12,582,912
    float* Zp   = (float*)(ws + 111267840);    //      786,432
    float* Zrn  = (float*)(ws + 112054272);    //      786,432
    float* NegL = (float*)(ws + 112840704);    //    4,194,304
    float* tP   = (float*)(ws + 117035008);    // small vectors (256 floats each)
    float* tM   = tP + 256;
    float* spP  = tP + 512;
    float* spM  = tP + 768;
    float* posL = tP + 1024;
    float* rowL = tP + 1280;
    float* recP = tP + 1536;
    (void)in_sizes; (void)n_in; (void)out_size; (void)ws_size;

    const dim3 blk(256);

    // ---- GEMM1 dual (ht@W1p | ht@W1m), split-K 32 each, grid 512 blocks
    gemm32t<0,0,0, VSZ, BOT, BOT, VSZ, 32><<<dim3(2,4,64), blk, 0, stream>>>(
        ht, ht, W1p, W1m, P, P1g, nullptr, nullptr);
    reduce_bias_gelu2<<<dim3(512,2), blk, 0, stream>>>(
        P, P1g, b1p, b1m, Hp, Hm, BATCH*BOT, BOT, 32);

    // ---- GEMM2 dual (Hp@W2p | Hm@W2m), fused softplus+bias, grid 956 blocks
    gemm32t<0,1,1, BOT, VSZ, VSZ, BOT, 1><<<dim3(2,239,2), blk, 0, stream>>>(
        Hp, Hm, W2p, W2m, U1, U2, b2p, b2m);

    // ---- exact top-K thresholds (both branches, one launch)
    topk_thresh2<<<dim3(2,256), dim3(TKT), 0, stream>>>(U1, U2, tP, tM);
    build_sq<<<dim3(256), blk, 0, stream>>>(U1, U2, sr, tP, tM, spP, spM);

    // ---- decode dual (sq@Wdec | sr@Wdec), split-K 32, grid 768 blocks
    //      branch-p partials -> P, branch-m partials -> dead U2 region
    gemm32t<0,0,0, VSZ, DIM, DIM, VSZ, 32><<<dim3(2,6,64), blk, 0, stream>>>(
        U1, sr, Wdec, Wdec, P, U2, nullptr, nullptr);
    reduce_sum_parts<<<dim3(768), blk, 0, stream>>>(P,  Y1, BATCH*DIM, 32);
    reduce_sum_parts<<<dim3(768), blk, 0, stream>>>(U2, Y2, BATCH*DIM, 32);

    // ---- normalizations
    rownorm<<<dim3(256),  blk, 0, stream>>>(Y1, Y1, 1);   // zq (double norm)
    rownorm<<<dim3(256),  blk, 0, stream>>>(Y2, Y2, 0);   // zhat_r
    rownorm<<<dim3(4096), blk, 0, stream>>>(zneg, Zn, 0);
    rownorm<<<dim3(256),  blk, 0, stream>>>(zpos, Zp, 0);
    rownorm<<<dim3(256),  blk, 0, stream>>>(zr,   Zrn, 0);

    // ---- retrieval loss
    pos_dot<<<dim3(256), blk, 0, stream>>>(Y1, Zp, posL);
    gemm32t<1,0,0, DIM, DIM, MNEG, DIM, 4><<<dim3(2,32,4), blk, 0, stream>>>(
        Y1, Y1, Zn, Zn, P, P, nullptr, nullptr);
    reduce_sum_parts<<<dim3(4096), blk, 0, stream>>>(P, NegL, BATCH*MNEG, 4);
    lse_loss<<<dim3(256), blk, 0, stream>>>(NegL, posL, rowL);

    // ---- reconstruction loss
    rec_row<<<dim3(256), blk, 0, stream>>>(Y2, Zrn, recP);

    // ---- combine
    final_combine<<<dim3(1), blk, 0, stream>>>(rowL, recP, spP, spM, out);
}